// Round 13
// baseline (595.351 us; speedup 1.0000x reference)
//
#include <hip/hip_runtime.h>
#include <math.h>

// VQ-VAE forward. R25: k_fix_border folded into k_enc_comp's epilogue — each
// border pixel is produced by exactly one enc_comp thread, which subtracts the
// border correction from its in-register f32 value BEFORE the single f2bf
// (replaces the old double-quantize RMW; strictly closer to f32 reference).
// Deletes one kernel + launch gap + the X0 RMW round trip. Launches 10 -> 9.
// Everything else byte-identical to R24 (492.1 µs, absmax 0.01887512).

typedef unsigned short ushort;
typedef short bf16x8 __attribute__((ext_vector_type(8)));
typedef float f32x4 __attribute__((ext_vector_type(4)));

__device__ __forceinline__ ushort f2bf(float f) {
    unsigned u = __builtin_bit_cast(unsigned, f);
    unsigned r = (u + 0x7fffu + ((u >> 16) & 1u)) >> 16;
    return (ushort)r;
}
__device__ __forceinline__ float bfl(unsigned u) { return __builtin_bit_cast(float, u << 16); }
__device__ __forceinline__ float bfh(unsigned u) { return __builtin_bit_cast(float, u & 0xffff0000u); }

__device__ __forceinline__ unsigned relu_u(unsigned u) {
    unsigned m = (u >> 15) & 0x00010001u;
    return u & ~((m << 16) - m);
}
__device__ __forceinline__ uint4 relu4(uint4 v) {
    v.x = relu_u(v.x); v.y = relu_u(v.y); v.z = relu_u(v.z); v.w = relu_u(v.w);
    return v;
}

// ======================= merged prep: packs + xpack + zeroing =======================
// blockIdx ranges: [0,9216) c3x4 | [9216,10240) c1x1x4 | [10240,10305) vq pack
// | [10305,26689) xpack | [26689,26743) zero wdec | 26743 zero loss.
__global__ void k_prep(const float* __restrict__ w30, const float* __restrict__ w31,
                       const float* __restrict__ w32, const float* __restrict__ w33,
                       ushort* __restrict__ o30, ushort* __restrict__ o31,
                       ushort* __restrict__ o32, ushort* __restrict__ o33,
                       const float* __restrict__ w10, const float* __restrict__ w11,
                       const float* __restrict__ w12, const float* __restrict__ w13,
                       ushort* __restrict__ o10, ushort* __restrict__ o11,
                       ushort* __restrict__ o12, ushort* __restrict__ o13,
                       const float* __restrict__ cbk, ushort* __restrict__ apk,
                       float* __restrict__ en,
                       const float* __restrict__ x, ushort* __restrict__ xpk,
                       ushort* __restrict__ wdec, float* __restrict__ loss) {
    int b = blockIdx.x, tid = threadIdx.x;
    if (b < 9216) {                                   // ---- pack c3x4 ----
        int layer = b / 2304;
        int i = (b - layer * 2304) * 256 + tid;       // 589824
        const float* w = layer == 0 ? w30 : layer == 1 ? w31 : layer == 2 ? w32 : w33;
        ushort* o = layer == 0 ? o30 : layer == 1 ? o31 : layer == 2 ? o32 : o33;
        int kk = i & 31, co = (i >> 5) & 255, cb = (i >> 13) & 7, t = i >> 16;
        int ci = cb * 32 + kk, kh = t / 3, kw = t % 3;
        o[i] = f2bf(w[((co * 256 + ci) * 3 + kh) * 3 + kw]);
    } else if (b < 10240) {                           // ---- pack c1x1x4 ----
        int lb = b - 9216;
        int layer = lb >> 8;
        int i = (lb & 255) * 256 + tid;               // 65536
        const float* w = layer == 0 ? w10 : layer == 1 ? w11 : layer == 2 ? w12 : w13;
        ushort* o = layer == 0 ? o10 : layer == 1 ? o11 : layer == 2 ? o12 : o13;
        int kk = i & 31, co = (i >> 5) & 255, cb = (i >> 13) & 7;
        o[i] = f2bf(w[co * 256 + cb * 32 + kk]);
    } else if (b < 10305) {                           // ---- pack vq ----
        int lb = b - 10240;
        if (lb < 64) {
            int i = lb * 256 + tid;
            int j = i & 7, lane = (i >> 3) & 63, s = (i >> 9) & 1, t = i >> 10;
            int code = t * 16 + (lane & 15);
            int dim = s * 32 + (lane >> 4) * 8 + j;
            apk[i] = f2bf(cbk[code * 64 + dim]);
        } else {
            int code = tid;
            float s = 0.f;
            for (int d = 0; d < 64; ++d) { float v = cbk[code * 64 + d]; s += v * v; }
            en[code] = s;
        }
    } else if (b < 26689) {                           // ---- xpack ----
        int i = (b - 10305) * 256 + tid;              // 4,194,304
        int j = i & 7, ow = (i >> 3) & 31, q = (i >> 8) & 3, r = (i >> 10) & 127, n = i >> 17;
        int k = q * 8 + j;
        float v = 0.f;
        if (k < 30) {
            int ci = k % 3, kw = k / 3;
            int col = 4 * ow - 3 + kw;
            if ((unsigned)col < 128u) v = x[((n * 3 + ci) * 128 + r) * 128 + col];
        }
        xpk[i] = f2bf(v);
    } else if (b < 26743) {                           // ---- zero wdec ----
        int idx = (b - 26689) * 256 + tid;            // 13824 x 16B = 221184 B
        uint4 z; z.x = 0; z.y = 0; z.z = 0; z.w = 0;
        *(uint4*)(wdec + idx * 8) = z;
    } else {                                          // ---- zero loss ----
        if (tid == 0) loss[0] = 0.f;
    }
}

// ======================= merged weight composition (enc | dec) ==================
__global__ __launch_bounds__(256) void k_wcomp(const float* __restrict__ w1,
                                               const float* __restrict__ b1f,
                                               const float* __restrict__ w2,
                                               const float* __restrict__ b2f,
                                               ushort* __restrict__ wenc,
                                               float* __restrict__ benc,
                                               float* __restrict__ wct,
                                               float* __restrict__ wcb,
                                               float* __restrict__ wcl,
                                               float* __restrict__ wcr,
                                               float* __restrict__ wcc,
                                               const float* __restrict__ dt1,
                                               const float* __restrict__ dt1b,
                                               const float* __restrict__ dt2,
                                               const float* __restrict__ dt2b,
                                               ushort* __restrict__ wdec,
                                               float* __restrict__ bdec) {
    __shared__ float sA[12288];
    __shared__ float sB[4096];
    __shared__ float part[2400];
    int tid = threadIdx.x;

    if (blockIdx.x < 256) {
        // ================= encoder branch (sw1 = sA, sw2 = sB) =================
        int co = blockIdx.x;
        for (int i = tid; i < 12288; i += 256) sA[i] = w1[i];
        for (int i = tid; i < 4096; i += 256) sB[i] = w2[co * 4096 + i];
        __syncthreads();

        {   // bias
            float s = 0.f;
#pragma unroll
            for (int t = 0; t < 16; ++t) s += sB[tid * 16 + t];
            float pb = b1f[tid] * s;
#pragma unroll
            for (int m = 1; m < 64; m <<= 1) pb += __shfl_xor(pb, m);
            if ((tid & 63) == 0) part[tid >> 6] = pb;
        }
        __syncthreads();
        if (tid == 0) benc[co] = b2f[co] + part[0] + part[1] + part[2] + part[3];

        if (tid < 240) {               // t = y*24 + ci*8 + ms
            int y = tid / 24, rem = tid % 24, ci = rem / 8, ms = rem % 8;
            int na = 0, aa[2], h1[2];
#pragma unroll
            for (int a = 0; a < 4; ++a) {
                int k1 = y - 2 * a;
                if ((unsigned)k1 < 4u) { aa[na] = a; h1[na] = k1; ++na; }
            }
            float acc10[10];
#pragma unroll
            for (int xx = 0; xx < 10; ++xx) acc10[xx] = 0.f;
            for (int m = ms * 32; m < ms * 32 + 32; ++m) {
                for (int pa = 0; pa < na; ++pa) {
                    float4 a2 = *(const float4*)&sB[m * 16 + aa[pa] * 4];
                    float4 a1 = *(const float4*)&sA[m * 48 + ci * 16 + h1[pa] * 4];
                    acc10[0] += a2.x * a1.x; acc10[1] += a2.x * a1.y; acc10[2] += a2.x * a1.z; acc10[3] += a2.x * a1.w;
                    acc10[2] += a2.y * a1.x; acc10[3] += a2.y * a1.y; acc10[4] += a2.y * a1.z; acc10[5] += a2.y * a1.w;
                    acc10[4] += a2.z * a1.x; acc10[5] += a2.z * a1.y; acc10[6] += a2.z * a1.z; acc10[7] += a2.z * a1.w;
                    acc10[6] += a2.w * a1.x; acc10[7] += a2.w * a1.y; acc10[8] += a2.w * a1.z; acc10[9] += a2.w * a1.w;
                }
            }
#pragma unroll
            for (int xx = 0; xx < 10; ++xx) part[tid * 10 + xx] = acc10[xx];
        }
        __syncthreads();
        for (int w = tid; w < 320; w += 256) {
            if (w < 300) {
                int y = w / 30, r = w % 30, ci = r / 10, xx = r % 10;
                float s = 0.f;
#pragma unroll
                for (int ms = 0; ms < 8; ++ms) s += part[((y * 24 + ci * 8) + ms) * 10 + xx];
                wenc[(y * 256 + co) * 32 + xx * 3 + ci] = f2bf(s);
            } else {
                int j = w - 300;
                int y = j >> 1;
                wenc[(y * 256 + co) * 32 + 30 + (j & 1)] = 0;
            }
        }

        // ---- border-correction weights from LDS ----
        if (tid < 30 || (tid >= 32 && tid < 62)) {
            bool top = tid < 30;
            int t = top ? tid : tid - 32;
            int xx = t / 3, ci = t % 3;
            int k2hf = top ? 0 : 3, k1hf = top ? 3 : 0;
            float s = 0.f;
            for (int m = 0; m < 256; ++m)
                for (int k2w = 0; k2w < 4; ++k2w) {
                    int k1w = xx - 2 * k2w;
                    if ((unsigned)k1w < 4u)
                        s += sB[m * 16 + k2hf * 4 + k2w] * sA[m * 48 + ci * 16 + k1hf * 4 + k1w];
                }
            (top ? wct : wcb)[t * 256 + co] = s;
        } else if ((tid >= 64 && tid < 94) || (tid >= 96 && tid < 126)) {
            bool left = tid < 94;
            int t = left ? tid - 64 : tid - 96;
            int y = t / 3, ci = t % 3;
            int k2wf = left ? 0 : 3, k1wf = left ? 3 : 0;
            float s = 0.f;
            for (int m = 0; m < 256; ++m)
                for (int k2h = 0; k2h < 4; ++k2h) {
                    int k1h = y - 2 * k2h;
                    if ((unsigned)k1h < 4u)
                        s += sB[m * 16 + k2h * 4 + k2wf] * sA[m * 48 + ci * 16 + k1h * 4 + k1wf];
                }
            (left ? wcl : wcr)[t * 256 + co] = s;
        } else if (tid >= 128 && tid < 140) {
            int c = (tid - 128) / 3, ci = (tid - 128) % 3;
            int k2h = (c >> 1) ? 3 : 0, k2w = (c & 1) ? 3 : 0;
            int k1h = 3 - k2h, k1w = 3 - k2w;
            float s = 0.f;
            for (int m = 0; m < 256; ++m)
                s += sB[m * 16 + k2h * 4 + k2w] * sA[m * 48 + ci * 16 + k1h * 4 + k1w];
            wcc[(c * 3 + ci) * 256 + co] = s;
        }
    } else {
        // ================= decoder branch (s2 = sA, s1 = sB) =================
        int ci = blockIdx.x - 256;
        for (int i = tid; i < 4096; i += 256) sB[i] = dt1[ci * 4096 + i];
        for (int i = tid; i < 12288; i += 256) sA[i] = dt2[i];
        __syncthreads();

        if (ci == 0 && tid < 48) {
            int o = tid >> 4, p = tid & 15, py = p >> 2, px = p & 3;
            int c0 = (py + 1) & 1, d0 = (px + 1) & 1;
            float s = dt2b[o];
            for (int m = 0; m < 256; ++m) {
                float t2 = sA[m * 48 + o * 16 + c0 * 4 + d0] + sA[m * 48 + o * 16 + c0 * 4 + d0 + 2]
                         + sA[m * 48 + o * 16 + (c0 + 2) * 4 + d0] + sA[m * 48 + o * 16 + (c0 + 2) * 4 + d0 + 2];
                s += dt1b[m] * t2;
            }
            bdec[tid] = s;
        }

        if (tid < 240) {
            int y = tid / 24, rem = tid % 24, o = rem / 8, ms = rem % 8;
            int na = 0, aa[2], cc[2];
#pragma unroll
            for (int a = 0; a < 4; ++a) {
                int c = y - 2 * a;
                if ((unsigned)c < 4u) { aa[na] = a; cc[na] = c; ++na; }
            }
            float acc10[10];
#pragma unroll
            for (int xx = 0; xx < 10; ++xx) acc10[xx] = 0.f;
            for (int m = ms * 32; m < ms * 32 + 32; ++m) {
                for (int pa = 0; pa < na; ++pa) {
                    float4 d1 = *(const float4*)&sB[m * 16 + aa[pa] * 4];
                    float4 d2 = *(const float4*)&sA[m * 48 + o * 16 + cc[pa] * 4];
                    acc10[0] += d1.x * d2.x; acc10[1] += d1.x * d2.y; acc10[2] += d1.x * d2.z; acc10[3] += d1.x * d2.w;
                    acc10[2] += d1.y * d2.x; acc10[3] += d1.y * d2.y; acc10[4] += d1.y * d2.z; acc10[5] += d1.y * d2.w;
                    acc10[4] += d1.z * d2.x; acc10[5] += d1.z * d2.y; acc10[6] += d1.z * d2.z; acc10[7] += d1.z * d2.w;
                    acc10[6] += d1.w * d2.x; acc10[7] += d1.w * d2.y; acc10[8] += d1.w * d2.z; acc10[9] += d1.w * d2.w;
                }
            }
#pragma unroll
            for (int xx = 0; xx < 10; ++xx) part[tid * 10 + xx] = acc10[xx];
        }
        __syncthreads();
        for (int w = tid; w < 300; w += 256) {
            int y = w / 30, r = w % 30, o = r / 10, xx = r % 10;
            float s = 0.f;
#pragma unroll
            for (int ms = 0; ms < 8; ++ms) s += part[((y * 24 + o * 8) + ms) * 10 + xx];
            int du = (y < 3) ? 1 : (y < 7) ? 0 : -1;
            int py = y - 3 + 4 * du;
            int dv = (xx < 3) ? 1 : (xx < 7) ? 0 : -1;
            int px = xx - 3 + 4 * dv;
            int t = (du + 1) * 3 + (dv + 1);
            int cb2 = ci >> 5, kk = ci & 31;
            wdec[((((t * 3 + o) * 8 + cb2) * 16 + py * 4 + px) * 32) + kk] = f2bf(s);
        }
    }
}

// ======================= composed encoder conv + fused border fix ==============
// 3->256 k10 s4, 128->32. Border correction applied in-register before the
// single f2bf (replaces the old k_fix_border RMW; same correction sums, same
// per-k accumulation order).
__global__ __launch_bounds__(128) void k_enc_comp(const ushort* __restrict__ xpk,
                                                  const ushort* __restrict__ wenc,
                                                  const float* __restrict__ benc,
                                                  const float* __restrict__ x,
                                                  const float* __restrict__ wct,
                                                  const float* __restrict__ wcb,
                                                  const float* __restrict__ wcl,
                                                  const float* __restrict__ wcr,
                                                  const float* __restrict__ wcc,
                                                  ushort* __restrict__ obf) {
    int tid = threadIdx.x, lane = tid & 63, wv = tid >> 6;
    int q = lane >> 4, l15 = lane & 15;
    int b = blockIdx.x;
    int mblk = b & 7, coslab = (b >> 3) & 3, n = b >> 5;
    int R0 = mblk * 4 + wv * 2;
    int aoff = (coslab * 64 + l15) * 32 + q * 8;

    f32x4 acc[4][4];
#pragma unroll
    for (int at = 0; at < 4; ++at)
#pragma unroll
        for (int bt = 0; bt < 4; ++bt) acc[at][bt] = 0.f;

    for (int t = 0; t < 10; ++t) {
        bf16x8 af[4];
#pragma unroll
        for (int at = 0; at < 4; ++at)
            af[at] = *(const bf16x8*)(wenc + t * 8192 + aoff + at * 512);
#pragma unroll
        for (int bt2 = 0; bt2 < 2; ++bt2) {
            int irow = 4 * (R0 + bt2) + t - 3;
            if ((unsigned)irow >= 128u) continue;      // x zero padding -> skip
            bf16x8 bf[2];
#pragma unroll
            for (int hb = 0; hb < 2; ++hb) {
                int ow = hb * 16 + l15;
                bf[hb] = *(const bf16x8*)(xpk + ((((long)n * 128 + irow) * 4 + q) * 32 + ow) * 8);
            }
#pragma unroll
            for (int at = 0; at < 4; ++at)
#pragma unroll
                for (int hb = 0; hb < 2; ++hb)
                    acc[at][bt2 * 2 + hb] = __builtin_amdgcn_mfma_f32_16x16x32_bf16(
                        af[at], bf[hb], acc[at][bt2 * 2 + hb], 0, 0, 0);
        }
    }

    // ---- correction helpers (same sums/order as old k_fix_border) ----
    auto addTB = [&](const float* __restrict__ w, int row, int qq, int co_t, float* c4) {
        const ushort* xr = xpk + ((long)n * 128 + row) * 1024;   // [q(4)][ow(32)][8]
        for (int k = 0; k < 30; ++k) {
            float xv = bfl((unsigned)xr[(k >> 3) * 256 + qq * 8 + (k & 7)]);
            float4 w4 = *(const float4*)&w[k * 256 + co_t];
            c4[0] += w4.x * xv; c4[1] += w4.y * xv; c4[2] += w4.z * xv; c4[3] += w4.w * xv;
        }
    };
    auto addLR = [&](const float* __restrict__ w, int p, int colofs, int co_t, float* c4) {
        for (int y = 0; y < 10; ++y) {
            int row = 4 * p - 3 + y;
            if ((unsigned)row >= 128u) continue;
            for (int ci = 0; ci < 3; ++ci) {
                float xv = x[((long)(n * 3 + ci) * 128 + row) * 128 + colofs];
                float4 w4 = *(const float4*)&w[(y * 3 + ci) * 256 + co_t];
                c4[0] += w4.x * xv; c4[1] += w4.y * xv; c4[2] += w4.z * xv; c4[3] += w4.w * xv;
            }
        }
    };
    auto subC = [&](int c, int row, int colofs, int co_t, float* c4) {
        for (int ci = 0; ci < 3; ++ci) {
            float xv = x[((long)(n * 3 + ci) * 128 + row) * 128 + colofs];
            float4 w4 = *(const float4*)&wcc[(c * 3 + ci) * 256 + co_t];
            c4[0] -= w4.x * xv; c4[1] -= w4.y * xv; c4[2] -= w4.z * xv; c4[3] -= w4.w * xv;
        }
    };

    int co_base = coslab * 64;
#pragma unroll
    for (int at = 0; at < 4; ++at) {
        int co_t = co_base + at * 16 + q * 4;
        float4 b4 = *(const float4*)(benc + co_t);
        float bv[4] = {b4.x, b4.y, b4.z, b4.w};
#pragma unroll
        for (int bt = 0; bt < 4; ++bt) {
            int ofs = bt * 16 + l15;
            int m = R0 * 32 + ofs;
            long oaddr = ((long)n * 1024 + m) * 256 + co_t;
            float v[4];
#pragma unroll
            for (int r = 0; r < 4; ++r) v[r] = acc[at][bt][r] + bv[r];
            int prow = R0 + (ofs >> 5), qq = ofs & 31;
            if (prow == 0 || prow == 31 || qq == 0 || qq == 31) {
                float c4[4] = {0.f, 0.f, 0.f, 0.f};
                if (prow == 0)  addTB(wct, 0, qq, co_t, c4);
                if (prow == 31) addTB(wcb, 127, qq, co_t, c4);
                if (qq == 0) {
                    addLR(wcl, prow, 0, co_t, c4);
                    if (prow == 0)  subC(0, 0, 0, co_t, c4);
                    if (prow == 31) subC(2, 127, 0, co_t, c4);
                }
                if (qq == 31) {
                    addLR(wcr, prow, 127, co_t, c4);
                    if (prow == 0)  subC(1, 0, 127, co_t, c4);
                    if (prow == 31) subC(3, 127, 127, co_t, c4);
                }
#pragma unroll
                for (int r = 0; r < 4; ++r) v[r] -= c4[r];
            }
            uint2 pk;
            pk.x = (unsigned)f2bf(v[0]) | ((unsigned)f2bf(v[1]) << 16);
            pk.y = (unsigned)f2bf(v[2]) | ((unsigned)f2bf(v[3]) << 16);
            *(uint2*)(obf + oaddr) = pk;
        }
    }
}

// ======================= fused res block (R23: stage-once, barrier-free K) =====
__global__ __launch_bounds__(256, 2) void k_resblock(const ushort* __restrict__ xin,
                                                     const ushort* __restrict__ w3pk,
                                                     const ushort* __restrict__ w1pk,
                                                     ushort* __restrict__ obf) {
    __shared__ __align__(16) ushort sS[4 * 32 * 34 * 8];   // 69632 B

    int tid = threadIdx.x, lane = tid & 63, wv = tid >> 6;
    int q = lane >> 4, l15 = lane & 15;
    int b = blockIdx.x;                              // 32n * 16 rowpairs
    int rp = b & 15, n = b >> 4;
    int R0 = rp * 2;

    int brr[4], bcol[4];
#pragma unroll
    for (int bt = 0; bt < 4; ++bt) {
        int p = bt * 16 + l15;
        brr[bt] = p >> 5; bcol[bt] = (p & 31) + 1;
    }
    int aoff = (wv * 64 + l15) * 32 + q * 8;

    // ---- stage the whole tile: idx = ((r*32 + c)*32 + j), contiguous bursts ----
#pragma unroll
    for (int it = 0; it < 16; ++it) {
        int idx = it * 256 + tid;
        int j = idx & 31, c = (idx >> 5) & 31, r = idx >> 10;
        int hh2 = R0 - 1 + r;
        uint4 v;
        if ((unsigned)hh2 < 32u)
            v = relu4(*(const uint4*)(xin + (((long)n * 32 + hh2) * 32 + c) * 256 + j * 8));
        else { v.x = 0; v.y = 0; v.z = 0; v.w = 0; }
        *(uint4*)&sS[((r * 32 + j) * 34 + c + 1) * 8] = v;
    }
    {   // zero pads (cols 0, 33): one slot per thread, 256 = 4*32*2 exactly
        int r = tid >> 6, j = (tid >> 1) & 31, cc = (tid & 1) ? 33 : 0;
        uint4 z; z.x = 0; z.y = 0; z.z = 0; z.w = 0;
        *(uint4*)&sS[((r * 32 + j) * 34 + cc) * 8] = z;
    }

    f32x4 acc[4][4];
#pragma unroll
    for (int at = 0; at < 4; ++at)
#pragma unroll
        for (int bt = 0; bt < 4; ++bt) acc[at][bt] = 0.f;

    // A pipeline: rolling 3-buffer, depth 2, cross-cb (R22-verified)
    bf16x8 afA[3][4];
    {
        const ushort* wb0 = w3pk + aoff;
#pragma unroll
        for (int at = 0; at < 4; ++at) afA[0][at] = *(const bf16x8*)(wb0 + at * 512);
#pragma unroll
        for (int at = 0; at < 4; ++at) afA[1][at] = *(const bf16x8*)(wb0 + 65536 + at * 512);
    }
    __syncthreads();                                 // tile + pads visible

    // ---- 3x3: 8 cb x 9 taps, NO barriers ----
    for (int cb = 0; cb < 8; ++cb) {
        const ushort* wb = w3pk + (long)cb * 8192 + aoff;
        const ushort* wbn = w3pk + (long)(cb + 1) * 8192 + aoff;   // used if cb<7
        int qo = cb * 4 + q;                         // global ci-octet for this wave

#pragma unroll
        for (int t = 0; t < 9; ++t) {
            if (t < 7) {
#pragma unroll
                for (int at = 0; at < 4; ++at)
                    afA[(t + 2) % 3][at] = *(const bf16x8*)(wb + (long)(t + 2) * 65536 + at * 512);
            } else if (cb < 7) {
#pragma unroll
                for (int at = 0; at < 4; ++at)
                    afA[(t + 2) % 3][at] = *(const bf16x8*)(wbn + (long)(t - 7) * 65536 + at * 512);
            }
            int taprow = t / 3, dx = t % 3 - 1;
            bf16x8 bfr[4];
#pragma unroll
            for (int bt = 0; bt < 4; ++bt)
                bfr[bt] = *(const bf16x8*)&sS[(((brr[bt] + taprow) * 32 + qo) * 34 + bcol[bt] + dx) * 8];
#pragma unroll
            for (int at = 0; at < 4; ++at)
#pragma unroll
                for (int bt = 0; bt < 4; ++bt)
                    acc[at][bt] = __builtin_amdgcn_mfma_f32_16x16x32_bf16(afA[t % 3][at], bfr[bt],
                                                                          acc[at][bt], 0, 0, 0);
        }
    }
    __syncthreads();                                 // all sS reads done -> reuse

    // ---- 3x3 epilogue: relu -> bf16 -> exchange (aliased into sS) ----
#pragma unroll
    for (int at = 0; at < 4; ++at) {
        int co_t = wv * 64 + at * 16 + q * 4;
#pragma unroll
        for (int bt = 0; bt < 4; ++bt) {
            int px = bt * 16 + l15;
            uint2 pk;
            pk.x = (unsigned)f2bf(fmaxf(acc[at][bt][0], 0.f))
                 | ((unsigned)f2bf(fmaxf(acc[at][bt][1], 0.f)) << 16);
            pk.y = (unsigned)f2bf(fmaxf(acc[at][bt][2], 0.f))
                 | ((unsigned)f2bf(fmaxf(acc[at][bt][3], 0.f)) << 16);
            *(uint2*)&sS[px * 256 + (co_t ^ ((px & 7) << 3))] = pk;
        }
    }
    __syncthreads();

    // ---- 1x1 over 8 ci-slabs from exchange; distance-1 A-prefetch ----
    f32x4 acc2[4][4];
#pragma unroll
    for (int at = 0; at < 4; ++at)
#pragma unroll
        for (int bt = 0; bt < 4; ++bt) acc2[at][bt] = 0.f;

    bf16x8 af1c[4], af1n[4];
#pragma unroll
    for (int at = 0; at < 4; ++at) af1c[at] = *(const bf16x8*)(w1pk + aoff + at * 512);

    for (int cb = 0; cb < 8; ++cb) {
        if (cb + 1 < 8) {
            const ushort* wb1n = w1pk + (long)(cb + 1) * 8192 + aoff;
#pragma unroll
            for (int at = 0; at < 4; ++at) af1n[at] = *(const bf16x8*)(wb1n + at * 512);
        }
        bf16x8 bf1[4];
#pragma unroll
        for (int bt = 0; bt < 4; ++bt) {
            int px = bt * 16 + l15;
            bf1[bt] = *(const bf16x8*)&sS[px * 256 + ((cb * 32 + q * 8) ^ ((px & 7) << 3))];
        }
#pragma unroll
        for (int at = 0; at < 4; ++at)
#pragma unroll
            for (int bt = 0; bt < 4; ++bt)
                acc2[at][bt] = __builtin_amdgcn_mfma_f32_16x16x32_bf16(af1c[at], bf1[bt],
                                                                      acc2[at][bt], 0, 0, 0);
        if (cb + 1 < 8) {
#pragma unroll
            for (int at = 0; at < 4; ++at) af1c[at] = af1n[at];
        }
    }

#pragma unroll
    for (int at = 0; at < 4; ++at) {
        int co_t = wv * 64 + at * 16 + q * 4;
#pragma unroll
        for (int bt = 0; bt < 4; ++bt) {
            int m = R0 * 32 + bt * 16 + l15;
            long oaddr = ((long)n * 1024 + m) * 256 + co_t;
            uint2 rr = *(const uint2*)(xin + oaddr);
            float v[4];
            v[0] = acc2[at][bt][0] + bfl(rr.x);
            v[1] = acc2[at][bt][1] + bfh(rr.x);
            v[2] = acc2[at][bt][2] + bfl(rr.y);
            v[3] = acc2[at][bt][3] + bfh(rr.y);
            uint2 pk;
            pk.x = (unsigned)f2bf(v[0]) | ((unsigned)f2bf(v[1]) << 16);
            pk.y = (unsigned)f2bf(v[2]) | ((unsigned)f2bf(v[3]) << 16);
            *(uint2*)(obf + oaddr) = pk;
        }
    }
}

// ======================= VQ via MFMA (bf16 out) =======================
__global__ __launch_bounds__(256) void k_vq2(const ushort* __restrict__ zb,
                                             const ushort* __restrict__ apk,
                                             const float* __restrict__ en,
                                             const float* __restrict__ cbf,
                                             ushort* __restrict__ vqb,
                                             float* __restrict__ loss) {
    __shared__ int sIdx[64];
    __shared__ float sLoss[64];
    int tid = threadIdx.x, lane = tid & 63, wv = tid >> 6;
    int q = lane >> 4, l15 = lane & 15;
    int r0 = blockIdx.x * 64;
    int R = r0 + wv * 16;

    const ushort* zp = zb + ((long)(R + l15)) * 64 + q * 8;
    bf16x8 b0 = *(const bf16x8*)zp;
    bf16x8 b1 = *(const bf16x8*)(zp + 32);

    float z2 = 0.f;
    {
        const unsigned* u0 = (const unsigned*)&b0;
        const unsigned* u1 = (const unsigned*)&b1;
#pragma unroll
        for (int i = 0; i < 4; ++i) {
            float a = bfl(u0[i]), bb = bfh(u0[i]);
            float c = bfl(u1[i]), d = bfh(u1[i]);
            z2 += a * a + bb * bb + c * c + d * d;
        }
    }

    float best = 3.4e38f;
    int bidx = 0;
#pragma unroll
    for (int t = 0; t < 16; ++t) {
        bf16x8 a0 = *(const bf16x8*)(apk + ((t * 2 + 0) * 64 + lane) * 8);
        bf16x8 a1 = *(const bf16x8*)(apk + ((t * 2 + 1) * 64 + lane) * 8);
        f32x4 acc = {0.f, 0.f, 0.f, 0.f};
        acc = __builtin_amdgcn_mfma_f32_16x16x32_bf16(a0, b0, acc, 0, 0, 0);
        acc = __builtin_amdgcn_mfma_f32_16x16x32_bf16(a1, b1, acc, 0, 0, 0);
        float4 e4 = *(const float4*)(en + t * 16 + q * 4);
        float sc[4] = {e4.x - 2.f * acc[0], e4.y - 2.f * acc[1],
                       e4.z - 2.f * acc[2], e4.w - 2.f * acc[3]};
#pragma unroll
        for (int r = 0; r < 4; ++r) {
            int code = t * 16 + q * 4 + r;
            if (sc[r] < best) { best = sc[r]; bidx = code; }
        }
    }
#pragma unroll
    for (int m = 16; m <= 32; m <<= 1) {
        float ob = __shfl_xor(best, m);
        int oi = __shfl_xor(bidx, m);
        if (ob < best || (ob == best && oi < bidx)) { best = ob; bidx = oi; }
        z2 += __shfl_xor(z2, m);
    }
    if (q == 0) {
        sIdx[wv * 16 + l15] = bidx;
        sLoss[wv * 16 + l15] = best + z2;
    }
    __syncthreads();

    if (wv == 0) {
        float l = sLoss[lane];
#pragma unroll
        for (int m = 1; m < 64; m <<= 1) l += __shfl_xor(l, m);
        if (lane == 0) atomicAdd(loss, l * (1.25f / 8388608.f));
    }

    unsigned* vb = (unsigned*)(vqb + (long)r0 * 64);
#pragma unroll
    for (int k = 0; k < 8; ++k) {
        int i = k * 256 + tid;
        int rl = i >> 5, jp = i & 31;
        int idx = sIdx[rl];
        float v0 = cbf[idx * 64 + 2 * jp];
        float v1 = cbf[idx * 64 + 2 * jp + 1];
        vb[i] = (unsigned)f2bf(v0) | ((unsigned)f2bf(v1) << 16);
    }
}

// ======================= composed decoder deconv: 256->3 k10 s4, 32->128 ========
// Coalesced epilogue (verified bit-identical in R20).
__global__ __launch_bounds__(128, 2) void k_dec_comp(const ushort* __restrict__ xin,
                                                     const ushort* __restrict__ wdec,
                                                     const float* __restrict__ bdec,
                                                     float* __restrict__ out) {
    constexpr int BUFU = 3 * 4 * 34 * 8;             // 3264 ushorts
    constexpr int WLDS = 2 * BUFU;
    __shared__ __align__(16) ushort sX[2 * WLDS];    // 26112 B
    __shared__ __align__(16) float sOut[3072];       // 12288 B

    int tid = threadIdx.x, lane = tid & 63, wv = tid >> 6;
    int q = lane >> 4, l15 = lane & 15;
    int b = blockIdx.x;                              // 32n * 16rp
    int rp = b & 15, n = b >> 4;
    int U = rp * 2 + wv;
    ushort* sW = sX + wv * WLDS;

    if (lane < 48) {
        int cc = (lane & 1) ? 33 : 0;
        int sq = lane >> 1;
        uint4 z; z.x = z.y = z.z = z.w = 0;
        *(uint4*)&sW[(sq * 34 + cc) * 8] = z;
    }
    int scol = lane >> 1, j0 = (lane & 1) * 2;

    f32x4 acc[3][2];
#pragma unroll
    for (int o = 0; o < 3; ++o)
#pragma unroll
        for (int bt = 0; bt < 2; ++bt) acc[o][bt] = 0.f;

    uint4 sreg[3][2];
    auto stage_load = [&](int cb2) {
#pragma unroll
        for (int r = 0; r < 3; ++r) {
            int hh = U - 1 + r;
            bool valid = (unsigned)hh < 32u;
            long off = (((long)n * 32 + hh) * 32 + scol) * 256 + cb2 * 32 + j0 * 8;
#pragma unroll
            for (int k = 0; k < 2; ++k) {
                uint4 v;
                if (valid) v = *(const uint4*)(xin + off + k * 8);
                else { v.x = 0; v.y = 0; v.z = 0; v.w = 0; }
                sreg[r][k] = v;
            }
        }
    };
    auto write_stage = [&](int pbuf) {
        ushort* bufp = sW + pbuf * BUFU;
#pragma unroll
        for (int r = 0; r < 3; ++r)
#pragma unroll
            for (int k = 0; k < 2; ++k)
                *(uint4*)&bufp[((r * 4 + j0 + k) * 34 + scol + 1) * 8] = sreg[r][k];
    };

    stage_load(0);
    write_stage(0);

    for (int cb = 0; cb < 8; ++cb) {
        ushort* bufp = sW + (cb & 1) * BUFU;
        if (cb + 1 < 8) stage_load(cb + 1);
        const ushort* wb = wdec + (long)cb * 512 + l15 * 32 + q * 8;
#pragma unroll
        for (int t = 0; t < 9; ++t) {
            int du = t / 3 - 1, dv = t % 3 - 1;
            bf16x8 bfr[2];
#pragma unroll
            for (int bt = 0; bt < 2; ++bt)
                bfr[bt] = *(const bf16x8*)&bufp[(((du + 1) * 4 + q) * 34 + bt * 16 + l15 + 1 + dv) * 8];
#pragma unroll
            for (int o = 0; o < 3; ++o) {
                bf16x8 af = *(const bf16x8*)(wb + (long)(t * 3 + o) * 4096);
#pragma unroll
                for (int bt = 0; bt < 2; ++bt)
                    acc[o][bt] = __builtin_amdgcn_mfma_f32_16x16x32_bf16(af, bfr[bt], acc[o][bt], 0, 0, 0);
            }
        }
        if (cb + 1 < 8) write_stage((cb + 1) & 1);
    }

    // stage tanh'd output in LDS: sOut[((o*2+wv)*4+py)*128 + col]
#pragma unroll
    for (int o = 0; o < 3; ++o) {
#pragma unroll
        for (int bt = 0; bt < 2; ++bt) {
            int V = bt * 16 + l15;
#pragma unroll
            for (int r = 0; r < 4; ++r) {
                int p = q * 4 + r, py = p >> 2, px = p & 3;
                sOut[((o * 2 + wv) * 4 + py) * 128 + 4 * V + px] =
                    tanhf(acc[o][bt][r] + bdec[o * 16 + p]);
            }
        }
    }
    __syncthreads();

    // drain: 24 rows x 128 f32, 512B-contiguous bursts
#pragma unroll
    for (int i = 0; i < 6; ++i) {
        int idx = i * 128 + tid;                     // float4 index, 768 total
        int row = idx >> 5, colq = idx & 31;
        int o = row >> 3, rem = row & 7, wv2 = rem >> 2, py = rem & 3;
        long g = ((((long)n * 3 + o) * 128) + 4 * (rp * 2 + wv2) + py) * 128 + colq * 4;
        *(float4*)(out + g) = *(float4*)&sOut[row * 128 + colq * 4];
    }
}

// ======================= launcher =======================
extern "C" void kernel_launch(void* const* d_in, const int* in_sizes, int n_in,
                              void* d_out, int out_size, void* d_ws, size_t ws_size,
                              hipStream_t stream) {
    (void)in_sizes; (void)n_in; (void)out_size; (void)ws_size;
    const float* x        = (const float*)d_in[0];
    const float* enc_w1   = (const float*)d_in[1];
    const float* enc_b1   = (const float*)d_in[2];
    const float* enc_w2   = (const float*)d_in[3];
    const float* enc_b2   = (const float*)d_in[4];
    const float* er1_w3   = (const float*)d_in[5];
    const float* er1_w1   = (const float*)d_in[6];
    const float* er2_w3   = (const float*)d_in[7];
    const float* er2_w1   = (const float*)d_in[8];
    const float* codebook = (const float*)d_in[9];
    const float* dr1_w3   = (const float*)d_in[10];
    const float* dr1_w1   = (const float*)d_in[11];
    const float* dr2_w3   = (const float*)d_in[12];
    const float* dr2_w1   = (const float*)d_in[13];
    const float* dt1_w    = (const float*)d_in[14];
    const float* dt1_b    = (const float*)d_in[15];
    const float* dt2_w    = (const float*)d_in[16];
    const float* dt2_b    = (const float*)d_in[17];

    float* recon = (float*)d_out;
    float* loss  = recon + 1572864;

    char* ws = (char*)d_ws;
    size_t off = 0;
    auto alloc = [&](size_t bytes) { char* p = ws + off; off += (bytes + 255) & ~(size_t)255; return p; };
    ushort* X0   = (ushort*)alloc(16777216);   // bf16 NHWC 32x32 tensors
    ushort* X2   = (ushort*)alloc(16777216);
    ushort* X3   = (ushort*)alloc(16777216);
    ushort* X4   = (ushort*)alloc(16777216);
    ushort* xpk  = (ushort*)alloc(8388608);    // [32][128][4][32][8] bf16
    ushort* wpk_er13 = (ushort*)alloc(1179648);
    ushort* wpk_er23 = (ushort*)alloc(1179648);
    ushort* wpk_dr13 = (ushort*)alloc(1179648);
    ushort* wpk_dr23 = (ushort*)alloc(1179648);
    ushort* wpk_er11 = (ushort*)alloc(131072);
    ushort* wpk_er21 = (ushort*)alloc(131072);
    ushort* wpk_dr11 = (ushort*)alloc(131072);
    ushort* wpk_dr21 = (ushort*)alloc(131072);
    ushort* wenc     = (ushort*)alloc(163840); // [10][256][32] bf16
    ushort* wdec     = (ushort*)alloc(221184); // [9][3][8][16][32] bf16
    ushort* apk      = (ushort*)alloc(32768);
    float*  benc     = (float*)alloc(1024);
    float*  bdec     = (float*)alloc(192);
    float*  en       = (float*)alloc(1024);
    float*  wct      = (float*)alloc(32768);   // [30][256] f32 (transposed)
    float*  wcb      = (float*)alloc(32768);
    float*  wcl      = (float*)alloc(32768);
    float*  wcr      = (float*)alloc(32768);
    float*  wcc      = (float*)alloc(12288);   // [12][256] f32

    // merged prep: packs + xpack + wdec/loss zeroing
    k_prep<<<26744, 256, 0, stream>>>(er1_w3, er2_w3, dr1_w3, dr2_w3,
                                      wpk_er13, wpk_er23, wpk_dr13, wpk_dr23,
                                      er1_w1, er2_w1, dr1_w1, dr2_w1,
                                      wpk_er11, wpk_er21, wpk_dr11, wpk_dr21,
                                      codebook, apk, en, x, xpk, wdec, loss);
    // merged weight composition (enc | dec)
    k_wcomp<<<512, 256, 0, stream>>>(enc_w1, enc_b1, enc_w2, enc_b2, wenc, benc,
                                     wct, wcb, wcl, wcr, wcc,
                                     dt1_w, dt1_b, dt2_w, dt2_b, wdec, bdec);

    // encoder (composed conv1∘conv2 + fused border fix): x -> X0
    k_enc_comp<<<1024, 128, 0, stream>>>(xpk, wenc, benc, x,
                                         wct, wcb, wcl, wcr, wcc, X0);
    // fused res blocks (encoder)
    k_resblock<<<512, 256, 0, stream>>>(X0, wpk_er13, wpk_er11, X2);
    k_resblock<<<512, 256, 0, stream>>>(X2, wpk_er23, wpk_er21, X3);
    // VQ: X3 -> X4 (vq, no relu) + loss
    k_vq2<<<2048, 256, 0, stream>>>(X3, apk, en, codebook, X4, loss);
    // fused res blocks (decoder)
    k_resblock<<<512, 256, 0, stream>>>(X4, wpk_dr13, wpk_dr11, X0);
    k_resblock<<<512, 256, 0, stream>>>(X0, wpk_dr23, wpk_dr21, X2);
    // decoder (composed deconv1∘deconv2 + tanh): X2 -> recon
    k_dec_comp<<<512, 128, 0, stream>>>(X2, wdec, bdec, recon);
}

// Round 14
// 494.621 us; speedup vs baseline: 1.2036x; 1.2036x over previous
//
#include <hip/hip_runtime.h>
#include <math.h>

// VQ-VAE forward. R26: revert to R24 (verified 492.1 µs). R25's border-fix
// fold into k_enc_comp regressed 492->595: the cold correction path's
// runtime loops + divergence pushed VGPR 96->160, halving occupancy and
// serializing the epilogue (MfmaUtil 25->1.5%). Cold scalar paths belong in
// their own tiny kernel (k_fix_border, R19-verified). This source is
// byte-identical to R24.

typedef unsigned short ushort;
typedef short bf16x8 __attribute__((ext_vector_type(8)));
typedef float f32x4 __attribute__((ext_vector_type(4)));

__device__ __forceinline__ ushort f2bf(float f) {
    unsigned u = __builtin_bit_cast(unsigned, f);
    unsigned r = (u + 0x7fffu + ((u >> 16) & 1u)) >> 16;
    return (ushort)r;
}
__device__ __forceinline__ float bfl(unsigned u) { return __builtin_bit_cast(float, u << 16); }
__device__ __forceinline__ float bfh(unsigned u) { return __builtin_bit_cast(float, u & 0xffff0000u); }

__device__ __forceinline__ unsigned relu_u(unsigned u) {
    unsigned m = (u >> 15) & 0x00010001u;
    return u & ~((m << 16) - m);
}
__device__ __forceinline__ uint4 relu4(uint4 v) {
    v.x = relu_u(v.x); v.y = relu_u(v.y); v.z = relu_u(v.z); v.w = relu_u(v.w);
    return v;
}

// ======================= merged prep: packs + xpack + zeroing =======================
// blockIdx ranges: [0,9216) c3x4 | [9216,10240) c1x1x4 | [10240,10305) vq pack
// | [10305,26689) xpack | [26689,26743) zero wdec | 26743 zero loss.
__global__ void k_prep(const float* __restrict__ w30, const float* __restrict__ w31,
                       const float* __restrict__ w32, const float* __restrict__ w33,
                       ushort* __restrict__ o30, ushort* __restrict__ o31,
                       ushort* __restrict__ o32, ushort* __restrict__ o33,
                       const float* __restrict__ w10, const float* __restrict__ w11,
                       const float* __restrict__ w12, const float* __restrict__ w13,
                       ushort* __restrict__ o10, ushort* __restrict__ o11,
                       ushort* __restrict__ o12, ushort* __restrict__ o13,
                       const float* __restrict__ cbk, ushort* __restrict__ apk,
                       float* __restrict__ en,
                       const float* __restrict__ x, ushort* __restrict__ xpk,
                       ushort* __restrict__ wdec, float* __restrict__ loss) {
    int b = blockIdx.x, tid = threadIdx.x;
    if (b < 9216) {                                   // ---- pack c3x4 ----
        int layer = b / 2304;
        int i = (b - layer * 2304) * 256 + tid;       // 589824
        const float* w = layer == 0 ? w30 : layer == 1 ? w31 : layer == 2 ? w32 : w33;
        ushort* o = layer == 0 ? o30 : layer == 1 ? o31 : layer == 2 ? o32 : o33;
        int kk = i & 31, co = (i >> 5) & 255, cb = (i >> 13) & 7, t = i >> 16;
        int ci = cb * 32 + kk, kh = t / 3, kw = t % 3;
        o[i] = f2bf(w[((co * 256 + ci) * 3 + kh) * 3 + kw]);
    } else if (b < 10240) {                           // ---- pack c1x1x4 ----
        int lb = b - 9216;
        int layer = lb >> 8;
        int i = (lb & 255) * 256 + tid;               // 65536
        const float* w = layer == 0 ? w10 : layer == 1 ? w11 : layer == 2 ? w12 : w13;
        ushort* o = layer == 0 ? o10 : layer == 1 ? o11 : layer == 2 ? o12 : o13;
        int kk = i & 31, co = (i >> 5) & 255, cb = (i >> 13) & 7;
        o[i] = f2bf(w[co * 256 + cb * 32 + kk]);
    } else if (b < 10305) {                           // ---- pack vq ----
        int lb = b - 10240;
        if (lb < 64) {
            int i = lb * 256 + tid;
            int j = i & 7, lane = (i >> 3) & 63, s = (i >> 9) & 1, t = i >> 10;
            int code = t * 16 + (lane & 15);
            int dim = s * 32 + (lane >> 4) * 8 + j;
            apk[i] = f2bf(cbk[code * 64 + dim]);
        } else {
            int code = tid;
            float s = 0.f;
            for (int d = 0; d < 64; ++d) { float v = cbk[code * 64 + d]; s += v * v; }
            en[code] = s;
        }
    } else if (b < 26689) {                           // ---- xpack ----
        int i = (b - 10305) * 256 + tid;              // 4,194,304
        int j = i & 7, ow = (i >> 3) & 31, q = (i >> 8) & 3, r = (i >> 10) & 127, n = i >> 17;
        int k = q * 8 + j;
        float v = 0.f;
        if (k < 30) {
            int ci = k % 3, kw = k / 3;
            int col = 4 * ow - 3 + kw;
            if ((unsigned)col < 128u) v = x[((n * 3 + ci) * 128 + r) * 128 + col];
        }
        xpk[i] = f2bf(v);
    } else if (b < 26743) {                           // ---- zero wdec ----
        int idx = (b - 26689) * 256 + tid;            // 13824 x 16B = 221184 B
        uint4 z; z.x = 0; z.y = 0; z.z = 0; z.w = 0;
        *(uint4*)(wdec + idx * 8) = z;
    } else {                                          // ---- zero loss ----
        if (tid == 0) loss[0] = 0.f;
    }
}

// ======================= merged weight composition (enc | dec) ==================
// b < 256: encoder branch (co = b). b >= 256: decoder branch (ci = b-256).
// LDS shapes identical across branches: sA[12288], sB[4096], part[2400].
__global__ __launch_bounds__(256) void k_wcomp(const float* __restrict__ w1,
                                               const float* __restrict__ b1f,
                                               const float* __restrict__ w2,
                                               const float* __restrict__ b2f,
                                               ushort* __restrict__ wenc,
                                               float* __restrict__ benc,
                                               float* __restrict__ wct,
                                               float* __restrict__ wcb,
                                               float* __restrict__ wcl,
                                               float* __restrict__ wcr,
                                               float* __restrict__ wcc,
                                               const float* __restrict__ dt1,
                                               const float* __restrict__ dt1b,
                                               const float* __restrict__ dt2,
                                               const float* __restrict__ dt2b,
                                               ushort* __restrict__ wdec,
                                               float* __restrict__ bdec) {
    __shared__ float sA[12288];
    __shared__ float sB[4096];
    __shared__ float part[2400];
    int tid = threadIdx.x;

    if (blockIdx.x < 256) {
        // ================= encoder branch (sw1 = sA, sw2 = sB) =================
        int co = blockIdx.x;
        for (int i = tid; i < 12288; i += 256) sA[i] = w1[i];
        for (int i = tid; i < 4096; i += 256) sB[i] = w2[co * 4096 + i];
        __syncthreads();

        {   // bias
            float s = 0.f;
#pragma unroll
            for (int t = 0; t < 16; ++t) s += sB[tid * 16 + t];
            float pb = b1f[tid] * s;
#pragma unroll
            for (int m = 1; m < 64; m <<= 1) pb += __shfl_xor(pb, m);
            if ((tid & 63) == 0) part[tid >> 6] = pb;
        }
        __syncthreads();
        if (tid == 0) benc[co] = b2f[co] + part[0] + part[1] + part[2] + part[3];

        if (tid < 240) {               // t = y*24 + ci*8 + ms
            int y = tid / 24, rem = tid % 24, ci = rem / 8, ms = rem % 8;
            int na = 0, aa[2], h1[2];
#pragma unroll
            for (int a = 0; a < 4; ++a) {
                int k1 = y - 2 * a;
                if ((unsigned)k1 < 4u) { aa[na] = a; h1[na] = k1; ++na; }
            }
            float acc10[10];
#pragma unroll
            for (int xx = 0; xx < 10; ++xx) acc10[xx] = 0.f;
            for (int m = ms * 32; m < ms * 32 + 32; ++m) {
                for (int pa = 0; pa < na; ++pa) {
                    float4 a2 = *(const float4*)&sB[m * 16 + aa[pa] * 4];
                    float4 a1 = *(const float4*)&sA[m * 48 + ci * 16 + h1[pa] * 4];
                    acc10[0] += a2.x * a1.x; acc10[1] += a2.x * a1.y; acc10[2] += a2.x * a1.z; acc10[3] += a2.x * a1.w;
                    acc10[2] += a2.y * a1.x; acc10[3] += a2.y * a1.y; acc10[4] += a2.y * a1.z; acc10[5] += a2.y * a1.w;
                    acc10[4] += a2.z * a1.x; acc10[5] += a2.z * a1.y; acc10[6] += a2.z * a1.z; acc10[7] += a2.z * a1.w;
                    acc10[6] += a2.w * a1.x; acc10[7] += a2.w * a1.y; acc10[8] += a2.w * a1.z; acc10[9] += a2.w * a1.w;
                }
            }
#pragma unroll
            for (int xx = 0; xx < 10; ++xx) part[tid * 10 + xx] = acc10[xx];
        }
        __syncthreads();
        for (int w = tid; w < 320; w += 256) {
            if (w < 300) {
                int y = w / 30, r = w % 30, ci = r / 10, xx = r % 10;
                float s = 0.f;
#pragma unroll
                for (int ms = 0; ms < 8; ++ms) s += part[((y * 24 + ci * 8) + ms) * 10 + xx];
                wenc[(y * 256 + co) * 32 + xx * 3 + ci] = f2bf(s);
            } else {
                int j = w - 300;
                int y = j >> 1;
                wenc[(y * 256 + co) * 32 + 30 + (j & 1)] = 0;
            }
        }

        // ---- border-correction weights from LDS ----
        if (tid < 30 || (tid >= 32 && tid < 62)) {
            bool top = tid < 30;
            int t = top ? tid : tid - 32;
            int xx = t / 3, ci = t % 3;
            int k2hf = top ? 0 : 3, k1hf = top ? 3 : 0;
            float s = 0.f;
            for (int m = 0; m < 256; ++m)
                for (int k2w = 0; k2w < 4; ++k2w) {
                    int k1w = xx - 2 * k2w;
                    if ((unsigned)k1w < 4u)
                        s += sB[m * 16 + k2hf * 4 + k2w] * sA[m * 48 + ci * 16 + k1hf * 4 + k1w];
                }
            (top ? wct : wcb)[t * 256 + co] = s;
        } else if ((tid >= 64 && tid < 94) || (tid >= 96 && tid < 126)) {
            bool left = tid < 94;
            int t = left ? tid - 64 : tid - 96;
            int y = t / 3, ci = t % 3;
            int k2wf = left ? 0 : 3, k1wf = left ? 3 : 0;
            float s = 0.f;
            for (int m = 0; m < 256; ++m)
                for (int k2h = 0; k2h < 4; ++k2h) {
                    int k1h = y - 2 * k2h;
                    if ((unsigned)k1h < 4u)
                        s += sB[m * 16 + k2h * 4 + k2wf] * sA[m * 48 + ci * 16 + k1h * 4 + k1wf];
                }
            (left ? wcl : wcr)[t * 256 + co] = s;
        } else if (tid >= 128 && tid < 140) {
            int c = (tid - 128) / 3, ci = (tid - 128) % 3;
            int k2h = (c >> 1) ? 3 : 0, k2w = (c & 1) ? 3 : 0;
            int k1h = 3 - k2h, k1w = 3 - k2w;
            float s = 0.f;
            for (int m = 0; m < 256; ++m)
                s += sB[m * 16 + k2h * 4 + k2w] * sA[m * 48 + ci * 16 + k1h * 4 + k1w];
            wcc[(c * 3 + ci) * 256 + co] = s;
        }
    } else {
        // ================= decoder branch (s2 = sA, s1 = sB) =================
        int ci = blockIdx.x - 256;
        for (int i = tid; i < 4096; i += 256) sB[i] = dt1[ci * 4096 + i];
        for (int i = tid; i < 12288; i += 256) sA[i] = dt2[i];
        __syncthreads();

        if (ci == 0 && tid < 48) {
            int o = tid >> 4, p = tid & 15, py = p >> 2, px = p & 3;
            int c0 = (py + 1) & 1, d0 = (px + 1) & 1;
            float s = dt2b[o];
            for (int m = 0; m < 256; ++m) {
                float t2 = sA[m * 48 + o * 16 + c0 * 4 + d0] + sA[m * 48 + o * 16 + c0 * 4 + d0 + 2]
                         + sA[m * 48 + o * 16 + (c0 + 2) * 4 + d0] + sA[m * 48 + o * 16 + (c0 + 2) * 4 + d0 + 2];
                s += dt1b[m] * t2;
            }
            bdec[tid] = s;
        }

        if (tid < 240) {
            int y = tid / 24, rem = tid % 24, o = rem / 8, ms = rem % 8;
            int na = 0, aa[2], cc[2];
#pragma unroll
            for (int a = 0; a < 4; ++a) {
                int c = y - 2 * a;
                if ((unsigned)c < 4u) { aa[na] = a; cc[na] = c; ++na; }
            }
            float acc10[10];
#pragma unroll
            for (int xx = 0; xx < 10; ++xx) acc10[xx] = 0.f;
            for (int m = ms * 32; m < ms * 32 + 32; ++m) {
                for (int pa = 0; pa < na; ++pa) {
                    float4 d1 = *(const float4*)&sB[m * 16 + aa[pa] * 4];
                    float4 d2 = *(const float4*)&sA[m * 48 + o * 16 + cc[pa] * 4];
                    acc10[0] += d1.x * d2.x; acc10[1] += d1.x * d2.y; acc10[2] += d1.x * d2.z; acc10[3] += d1.x * d2.w;
                    acc10[2] += d1.y * d2.x; acc10[3] += d1.y * d2.y; acc10[4] += d1.y * d2.z; acc10[5] += d1.y * d2.w;
                    acc10[4] += d1.z * d2.x; acc10[5] += d1.z * d2.y; acc10[6] += d1.z * d2.z; acc10[7] += d1.z * d2.w;
                    acc10[6] += d1.w * d2.x; acc10[7] += d1.w * d2.y; acc10[8] += d1.w * d2.z; acc10[9] += d1.w * d2.w;
                }
            }
#pragma unroll
            for (int xx = 0; xx < 10; ++xx) part[tid * 10 + xx] = acc10[xx];
        }
        __syncthreads();
        for (int w = tid; w < 300; w += 256) {
            int y = w / 30, r = w % 30, o = r / 10, xx = r % 10;
            float s = 0.f;
#pragma unroll
            for (int ms = 0; ms < 8; ++ms) s += part[((y * 24 + o * 8) + ms) * 10 + xx];
            int du = (y < 3) ? 1 : (y < 7) ? 0 : -1;
            int py = y - 3 + 4 * du;
            int dv = (xx < 3) ? 1 : (xx < 7) ? 0 : -1;
            int px = xx - 3 + 4 * dv;
            int t = (du + 1) * 3 + (dv + 1);
            int cb2 = ci >> 5, kk = ci & 31;
            wdec[((((t * 3 + o) * 8 + cb2) * 16 + py * 4 + px) * 32) + kk] = f2bf(s);
        }
    }
}

// ======================= composed encoder conv: 3->256 k10 s4, 128->32 =========
__global__ __launch_bounds__(128) void k_enc_comp(const ushort* __restrict__ xpk,
                                                  const ushort* __restrict__ wenc,
                                                  const float* __restrict__ benc,
                                                  ushort* __restrict__ obf) {
    int tid = threadIdx.x, lane = tid & 63, wv = tid >> 6;
    int q = lane >> 4, l15 = lane & 15;
    int b = blockIdx.x;
    int mblk = b & 7, coslab = (b >> 3) & 3, n = b >> 5;
    int R0 = mblk * 4 + wv * 2;
    int aoff = (coslab * 64 + l15) * 32 + q * 8;

    f32x4 acc[4][4];
#pragma unroll
    for (int at = 0; at < 4; ++at)
#pragma unroll
        for (int bt = 0; bt < 4; ++bt) acc[at][bt] = 0.f;

    for (int t = 0; t < 10; ++t) {
        bf16x8 af[4];
#pragma unroll
        for (int at = 0; at < 4; ++at)
            af[at] = *(const bf16x8*)(wenc + t * 8192 + aoff + at * 512);
#pragma unroll
        for (int bt2 = 0; bt2 < 2; ++bt2) {
            int irow = 4 * (R0 + bt2) + t - 3;
            if ((unsigned)irow >= 128u) continue;      // x zero padding -> skip
            bf16x8 bf[2];
#pragma unroll
            for (int hb = 0; hb < 2; ++hb) {
                int ow = hb * 16 + l15;
                bf[hb] = *(const bf16x8*)(xpk + ((((long)n * 128 + irow) * 4 + q) * 32 + ow) * 8);
            }
#pragma unroll
            for (int at = 0; at < 4; ++at)
#pragma unroll
                for (int hb = 0; hb < 2; ++hb)
                    acc[at][bt2 * 2 + hb] = __builtin_amdgcn_mfma_f32_16x16x32_bf16(
                        af[at], bf[hb], acc[at][bt2 * 2 + hb], 0, 0, 0);
        }
    }

    int co_base = coslab * 64;
#pragma unroll
    for (int at = 0; at < 4; ++at) {
        int co_t = co_base + at * 16 + q * 4;
        float4 b4 = *(const float4*)(benc + co_t);
        float bv[4] = {b4.x, b4.y, b4.z, b4.w};
#pragma unroll
        for (int bt = 0; bt < 4; ++bt) {
            int m = R0 * 32 + bt * 16 + l15;
            long oaddr = ((long)n * 1024 + m) * 256 + co_t;
            float v[4];
#pragma unroll
            for (int r = 0; r < 4; ++r) v[r] = acc[at][bt][r] + bv[r];
            uint2 pk;
            pk.x = (unsigned)f2bf(v[0]) | ((unsigned)f2bf(v[1]) << 16);
            pk.y = (unsigned)f2bf(v[2]) | ((unsigned)f2bf(v[3]) << 16);
            *(uint2*)(obf + oaddr) = pk;
        }
    }
}

// ======================= border fix (parallel, R19-verified; xpk addr R22) =====
__global__ __launch_bounds__(256) void k_fix_border(const float* __restrict__ x,
                                                    const ushort* __restrict__ xpk,
                                                    const float* __restrict__ wct,
                                                    const float* __restrict__ wcb,
                                                    const float* __restrict__ wcl,
                                                    const float* __restrict__ wcr,
                                                    const float* __restrict__ wcc,
                                                    ushort* __restrict__ X0) {
    int b = blockIdx.x;
    int n = b >> 7, job = b & 127;
    if (job >= 124) return;
    int co = threadIdx.x;

    auto dot_tb = [&](const float* __restrict__ w, int row, int qq) -> float {
        const ushort* xr = xpk + ((long)n * 128 + row) * 1024;   // [q(4)][ow(32)][8]
        float s = 0.f;
        for (int k = 0; k < 30; ++k)
            s += w[k * 256 + co] * bfl((unsigned)xr[(k >> 3) * 256 + qq * 8 + (k & 7)]);
        return s;
    };
    auto dot_lr = [&](const float* __restrict__ w, int p, int colofs) -> float {
        float s = 0.f;
        for (int y = 0; y < 10; ++y) {
            int row = 4 * p - 3 + y;
            if ((unsigned)row >= 128u) continue;
            for (int ci = 0; ci < 3; ++ci)
                s += w[(y * 3 + ci) * 256 + co] * x[((long)(n * 3 + ci) * 128 + row) * 128 + colofs];
        }
        return s;
    };
    auto corner = [&](int c, int row, int colofs) -> float {
        float s = 0.f;
        for (int ci = 0; ci < 3; ++ci)
            s += wcc[(c * 3 + ci) * 256 + co] * x[((long)(n * 3 + ci) * 128 + row) * 128 + colofs];
        return s;
    };

    int m;
    float corr;
    if (job < 32) {                       // top row p=0
        int qq = job;
        m = qq;
        corr = dot_tb(wct, 0, qq);
        if (qq == 0)  corr += dot_lr(wcl, 0, 0)   - corner(0, 0, 0);
        if (qq == 31) corr += dot_lr(wcr, 0, 127) - corner(1, 0, 127);
    } else if (job < 64) {                // bottom row p=31
        int qq = job - 32;
        m = 992 + qq;
        corr = dot_tb(wcb, 127, qq);
        if (qq == 0)  corr += dot_lr(wcl, 31, 0)   - corner(2, 127, 0);
        if (qq == 31) corr += dot_lr(wcr, 31, 127) - corner(3, 127, 127);
    } else if (job < 94) {                // left col q=0, p=1..30
        int p = job - 63;
        m = 32 * p;
        corr = dot_lr(wcl, p, 0);
    } else {                              // right col q=31, p=1..30
        int p = job - 93;
        m = 32 * p + 31;
        corr = dot_lr(wcr, p, 127);
    }

    ushort* ptr = X0 + ((long)n * 1024 + m) * 256 + co;
    float v = bfl((unsigned)(*ptr));
    *ptr = f2bf(v - corr);
}

// ======================= fused res block (R23: stage-once, barrier-free K) =====
__global__ __launch_bounds__(256, 2) void k_resblock(const ushort* __restrict__ xin,
                                                     const ushort* __restrict__ w3pk,
                                                     const ushort* __restrict__ w1pk,
                                                     ushort* __restrict__ obf) {
    __shared__ __align__(16) ushort sS[4 * 32 * 34 * 8];   // 69632 B

    int tid = threadIdx.x, lane = tid & 63, wv = tid >> 6;
    int q = lane >> 4, l15 = lane & 15;
    int b = blockIdx.x;                              // 32n * 16 rowpairs
    int rp = b & 15, n = b >> 4;
    int R0 = rp * 2;

    int brr[4], bcol[4];
#pragma unroll
    for (int bt = 0; bt < 4; ++bt) {
        int p = bt * 16 + l15;
        brr[bt] = p >> 5; bcol[bt] = (p & 31) + 1;
    }
    int aoff = (wv * 64 + l15) * 32 + q * 8;

    // ---- stage the whole tile: idx = ((r*32 + c)*32 + j), contiguous bursts ----
#pragma unroll
    for (int it = 0; it < 16; ++it) {
        int idx = it * 256 + tid;
        int j = idx & 31, c = (idx >> 5) & 31, r = idx >> 10;
        int hh2 = R0 - 1 + r;
        uint4 v;
        if ((unsigned)hh2 < 32u)
            v = relu4(*(const uint4*)(xin + (((long)n * 32 + hh2) * 32 + c) * 256 + j * 8));
        else { v.x = 0; v.y = 0; v.z = 0; v.w = 0; }
        *(uint4*)&sS[((r * 32 + j) * 34 + c + 1) * 8] = v;
    }
    {   // zero pads (cols 0, 33): one slot per thread, 256 = 4*32*2 exactly
        int r = tid >> 6, j = (tid >> 1) & 31, cc = (tid & 1) ? 33 : 0;
        uint4 z; z.x = 0; z.y = 0; z.z = 0; z.w = 0;
        *(uint4*)&sS[((r * 32 + j) * 34 + cc) * 8] = z;
    }

    f32x4 acc[4][4];
#pragma unroll
    for (int at = 0; at < 4; ++at)
#pragma unroll
        for (int bt = 0; bt < 4; ++bt) acc[at][bt] = 0.f;

    // A pipeline: rolling 3-buffer, depth 2, cross-cb (R22-verified)
    bf16x8 afA[3][4];
    {
        const ushort* wb0 = w3pk + aoff;
#pragma unroll
        for (int at = 0; at < 4; ++at) afA[0][at] = *(const bf16x8*)(wb0 + at * 512);
#pragma unroll
        for (int at = 0; at < 4; ++at) afA[1][at] = *(const bf16x8*)(wb0 + 65536 + at * 512);
    }
    __syncthreads();                                 // tile + pads visible

    // ---- 3x3: 8 cb x 9 taps, NO barriers ----
    for (int cb = 0; cb < 8; ++cb) {
        const ushort* wb = w3pk + (long)cb * 8192 + aoff;
        const ushort* wbn = w3pk + (long)(cb + 1) * 8192 + aoff;   // used if cb<7
        int qo = cb * 4 + q;                         // global ci-octet for this wave

#pragma unroll
        for (int t = 0; t < 9; ++t) {
            if (t < 7) {
#pragma unroll
                for (int at = 0; at < 4; ++at)
                    afA[(t + 2) % 3][at] = *(const bf16x8*)(wb + (long)(t + 2) * 65536 + at * 512);
            } else if (cb < 7) {
#pragma unroll
                for (int at = 0; at < 4; ++at)
                    afA[(t + 2) % 3][at] = *(const bf16x8*)(wbn + (long)(t - 7) * 65536 + at * 512);
            }
            int taprow = t / 3, dx = t % 3 - 1;
            bf16x8 bfr[4];
#pragma unroll
            for (int bt = 0; bt < 4; ++bt)
                bfr[bt] = *(const bf16x8*)&sS[(((brr[bt] + taprow) * 32 + qo) * 34 + bcol[bt] + dx) * 8];
#pragma unroll
            for (int at = 0; at < 4; ++at)
#pragma unroll
                for (int bt = 0; bt < 4; ++bt)
                    acc[at][bt] = __builtin_amdgcn_mfma_f32_16x16x32_bf16(afA[t % 3][at], bfr[bt],
                                                                          acc[at][bt], 0, 0, 0);
        }
    }
    __syncthreads();                                 // all sS reads done -> reuse

    // ---- 3x3 epilogue: relu -> bf16 -> exchange (aliased into sS) ----
#pragma unroll
    for (int at = 0; at < 4; ++at) {
        int co_t = wv * 64 + at * 16 + q * 4;
#pragma unroll
        for (int bt = 0; bt < 4; ++bt) {
            int px = bt * 16 + l15;
            uint2 pk;
            pk.x = (unsigned)f2bf(fmaxf(acc[at][bt][0], 0.f))
                 | ((unsigned)f2bf(fmaxf(acc[at][bt][1], 0.f)) << 16);
            pk.y = (unsigned)f2bf(fmaxf(acc[at][bt][2], 0.f))
                 | ((unsigned)f2bf(fmaxf(acc[at][bt][3], 0.f)) << 16);
            *(uint2*)&sS[px * 256 + (co_t ^ ((px & 7) << 3))] = pk;
        }
    }
    __syncthreads();

    // ---- 1x1 over 8 ci-slabs from exchange; distance-1 A-prefetch ----
    f32x4 acc2[4][4];
#pragma unroll
    for (int at = 0; at < 4; ++at)
#pragma unroll
        for (int bt = 0; bt < 4; ++bt) acc2[at][bt] = 0.f;

    bf16x8 af1c[4], af1n[4];
#pragma unroll
    for (int at = 0; at < 4; ++at) af1c[at] = *(const bf16x8*)(w1pk + aoff + at * 512);

    for (int cb = 0; cb < 8; ++cb) {
        if (cb + 1 < 8) {
            const ushort* wb1n = w1pk + (long)(cb + 1) * 8192 + aoff;
#pragma unroll
            for (int at = 0; at < 4; ++at) af1n[at] = *(const bf16x8*)(wb1n + at * 512);
        }
        bf16x8 bf1[4];
#pragma unroll
        for (int bt = 0; bt < 4; ++bt) {
            int px = bt * 16 + l15;
            bf1[bt] = *(const bf16x8*)&sS[px * 256 + ((cb * 32 + q * 8) ^ ((px & 7) << 3))];
        }
#pragma unroll
        for (int at = 0; at < 4; ++at)
#pragma unroll
            for (int bt = 0; bt < 4; ++bt)
                acc2[at][bt] = __builtin_amdgcn_mfma_f32_16x16x32_bf16(af1c[at], bf1[bt],
                                                                      acc2[at][bt], 0, 0, 0);
        if (cb + 1 < 8) {
#pragma unroll
            for (int at = 0; at < 4; ++at) af1c[at] = af1n[at];
        }
    }

#pragma unroll
    for (int at = 0; at < 4; ++at) {
        int co_t = wv * 64 + at * 16 + q * 4;
#pragma unroll
        for (int bt = 0; bt < 4; ++bt) {
            int m = R0 * 32 + bt * 16 + l15;
            long oaddr = ((long)n * 1024 + m) * 256 + co_t;
            uint2 rr = *(const uint2*)(xin + oaddr);
            float v[4];
            v[0] = acc2[at][bt][0] + bfl(rr.x);
            v[1] = acc2[at][bt][1] + bfh(rr.x);
            v[2] = acc2[at][bt][2] + bfl(rr.y);
            v[3] = acc2[at][bt][3] + bfh(rr.y);
            uint2 pk;
            pk.x = (unsigned)f2bf(v[0]) | ((unsigned)f2bf(v[1]) << 16);
            pk.y = (unsigned)f2bf(v[2]) | ((unsigned)f2bf(v[3]) << 16);
            *(uint2*)(obf + oaddr) = pk;
        }
    }
}

// ======================= VQ via MFMA (bf16 out) =======================
__global__ __launch_bounds__(256) void k_vq2(const ushort* __restrict__ zb,
                                             const ushort* __restrict__ apk,
                                             const float* __restrict__ en,
                                             const float* __restrict__ cbf,
                                             ushort* __restrict__ vqb,
                                             float* __restrict__ loss) {
    __shared__ int sIdx[64];
    __shared__ float sLoss[64];
    int tid = threadIdx.x, lane = tid & 63, wv = tid >> 6;
    int q = lane >> 4, l15 = lane & 15;
    int r0 = blockIdx.x * 64;
    int R = r0 + wv * 16;

    const ushort* zp = zb + ((long)(R + l15)) * 64 + q * 8;
    bf16x8 b0 = *(const bf16x8*)zp;
    bf16x8 b1 = *(const bf16x8*)(zp + 32);

    float z2 = 0.f;
    {
        const unsigned* u0 = (const unsigned*)&b0;
        const unsigned* u1 = (const unsigned*)&b1;
#pragma unroll
        for (int i = 0; i < 4; ++i) {
            float a = bfl(u0[i]), bb = bfh(u0[i]);
            float c = bfl(u1[i]), d = bfh(u1[i]);
            z2 += a * a + bb * bb + c * c + d * d;
        }
    }

    float best = 3.4e38f;
    int bidx = 0;
#pragma unroll
    for (int t = 0; t < 16; ++t) {
        bf16x8 a0 = *(const bf16x8*)(apk + ((t * 2 + 0) * 64 + lane) * 8);
        bf16x8 a1 = *(const bf16x8*)(apk + ((t * 2 + 1) * 64 + lane) * 8);
        f32x4 acc = {0.f, 0.f, 0.f, 0.f};
        acc = __builtin_amdgcn_mfma_f32_16x16x32_bf16(a0, b0, acc, 0, 0, 0);
        acc = __builtin_amdgcn_mfma_f32_16x16x32_bf16(a1, b1, acc, 0, 0, 0);
        float4 e4 = *(const float4*)(en + t * 16 + q * 4);
        float sc[4] = {e4.x - 2.f * acc[0], e4.y - 2.f * acc[1],
                       e4.z - 2.f * acc[2], e4.w - 2.f * acc[3]};
#pragma unroll
        for (int r = 0; r < 4; ++r) {
            int code = t * 16 + q * 4 + r;
            if (sc[r] < best) { best = sc[r]; bidx = code; }
        }
    }
#pragma unroll
    for (int m = 16; m <= 32; m <<= 1) {
        float ob = __shfl_xor(best, m);
        int oi = __shfl_xor(bidx, m);
        if (ob < best || (ob == best && oi < bidx)) { best = ob; bidx = oi; }
        z2 += __shfl_xor(z2, m);
    }
    if (q == 0) {
        sIdx[wv * 16 + l15] = bidx;
        sLoss[wv * 16 + l15] = best + z2;
    }
    __syncthreads();

    if (wv == 0) {
        float l = sLoss[lane];
#pragma unroll
        for (int m = 1; m < 64; m <<= 1) l += __shfl_xor(l, m);
        if (lane == 0) atomicAdd(loss, l * (1.25f / 8388608.f));
    }

    unsigned* vb = (unsigned*)(vqb + (long)r0 * 64);
#pragma unroll
    for (int k = 0; k < 8; ++k) {
        int i = k * 256 + tid;
        int rl = i >> 5, jp = i & 31;
        int idx = sIdx[rl];
        float v0 = cbf[idx * 64 + 2 * jp];
        float v1 = cbf[idx * 64 + 2 * jp + 1];
        vb[i] = (unsigned)f2bf(v0) | ((unsigned)f2bf(v1) << 16);
    }
}

// ======================= composed decoder deconv: 256->3 k10 s4, 32->128 ========
// Coalesced epilogue (verified bit-identical in R20).
__global__ __launch_bounds__(128, 2) void k_dec_comp(const ushort* __restrict__ xin,
                                                     const ushort* __restrict__ wdec,
                                                     const float* __restrict__ bdec,
                                                     float* __restrict__ out) {
    constexpr int BUFU = 3 * 4 * 34 * 8;             // 3264 ushorts
    constexpr int WLDS = 2 * BUFU;
    __shared__ __align__(16) ushort sX[2 * WLDS];    // 26112 B
    __shared__ __align__(16) float sOut[3072];       // 12288 B

    int tid = threadIdx.x, lane = tid & 63, wv = tid >> 6;
    int q = lane >> 4, l15 = lane & 15;
    int b = blockIdx.x;                              // 32n * 16rp
    int rp = b & 15, n = b >> 4;
    int U = rp * 2 + wv;
    ushort* sW = sX + wv * WLDS;

    if (lane < 48) {
        int cc = (lane & 1) ? 33 : 0;
        int sq = lane >> 1;
        uint4 z; z.x = z.y = z.z = z.w = 0;
        *(uint4*)&sW[(sq * 34 + cc) * 8] = z;
    }
    int scol = lane >> 1, j0 = (lane & 1) * 2;

    f32x4 acc[3][2];
#pragma unroll
    for (int o = 0; o < 3; ++o)
#pragma unroll
        for (int bt = 0; bt < 2; ++bt) acc[o][bt] = 0.f;

    uint4 sreg[3][2];
    auto stage_load = [&](int cb2) {
#pragma unroll
        for (int r = 0; r < 3; ++r) {
            int hh = U - 1 + r;
            bool valid = (unsigned)hh < 32u;
            long off = (((long)n * 32 + hh) * 32 + scol) * 256 + cb2 * 32 + j0 * 8;
#pragma unroll
            for (int k = 0; k < 2; ++k) {
                uint4 v;
                if (valid) v = *(const uint4*)(xin + off + k * 8);
                else { v.x = 0; v.y = 0; v.z = 0; v.w = 0; }
                sreg[r][k] = v;
            }
        }
    };
    auto write_stage = [&](int pbuf) {
        ushort* bufp = sW + pbuf * BUFU;
#pragma unroll
        for (int r = 0; r < 3; ++r)
#pragma unroll
            for (int k = 0; k < 2; ++k)
                *(uint4*)&bufp[((r * 4 + j0 + k) * 34 + scol + 1) * 8] = sreg[r][k];
    };

    stage_load(0);
    write_stage(0);

    for (int cb = 0; cb < 8; ++cb) {
        ushort* bufp = sW + (cb & 1) * BUFU;
        if (cb + 1 < 8) stage_load(cb + 1);
        const ushort* wb = wdec + (long)cb * 512 + l15 * 32 + q * 8;
#pragma unroll
        for (int t = 0; t < 9; ++t) {
            int du = t / 3 - 1, dv = t % 3 - 1;
            bf16x8 bfr[2];
#pragma unroll
            for (int bt = 0; bt < 2; ++bt)
                bfr[bt] = *(const bf16x8*)&bufp[(((du + 1) * 4 + q) * 34 + bt * 16 + l15 + 1 + dv) * 8];
#pragma unroll
            for (int o = 0; o < 3; ++o) {
                bf16x8 af = *(const bf16x8*)(wb + (long)(t * 3 + o) * 4096);
#pragma unroll
                for (int bt = 0; bt < 2; ++bt)
                    acc[o][bt] = __builtin_amdgcn_mfma_f32_16x16x32_bf16(af, bfr[bt], acc[o][bt], 0, 0, 0);
            }
        }
        if (cb + 1 < 8) write_stage((cb + 1) & 1);
    }

    // stage tanh'd output in LDS: sOut[((o*2+wv)*4+py)*128 + col]
#pragma unroll
    for (int o = 0; o < 3; ++o) {
#pragma unroll
        for (int bt = 0; bt < 2; ++bt) {
            int V = bt * 16 + l15;
#pragma unroll
            for (int r = 0; r < 4; ++r) {
                int p = q * 4 + r, py = p >> 2, px = p & 3;
                sOut[((o * 2 + wv) * 4 + py) * 128 + 4 * V + px] =
                    tanhf(acc[o][bt][r] + bdec[o * 16 + p]);
            }
        }
    }
    __syncthreads();

    // drain: 24 rows x 128 f32, 512B-contiguous bursts
#pragma unroll
    for (int i = 0; i < 6; ++i) {
        int idx = i * 128 + tid;                     // float4 index, 768 total
        int row = idx >> 5, colq = idx & 31;
        int o = row >> 3, rem = row & 7, wv2 = rem >> 2, py = rem & 3;
        long g = ((((long)n * 3 + o) * 128) + 4 * (rp * 2 + wv2) + py) * 128 + colq * 4;
        *(float4*)(out + g) = *(float4*)&sOut[row * 128 + colq * 4];
    }
}

// ======================= launcher =======================
extern "C" void kernel_launch(void* const* d_in, const int* in_sizes, int n_in,
                              void* d_out, int out_size, void* d_ws, size_t ws_size,
                              hipStream_t stream) {
    (void)in_sizes; (void)n_in; (void)out_size; (void)ws_size;
    const float* x        = (const float*)d_in[0];
    const float* enc_w1   = (const float*)d_in[1];
    const float* enc_b1   = (const float*)d_in[2];
    const float* enc_w2   = (const float*)d_in[3];
    const float* enc_b2   = (const float*)d_in[4];
    const float* er1_w3   = (const float*)d_in[5];
    const float* er1_w1   = (const float*)d_in[6];
    const float* er2_w3   = (const float*)d_in[7];
    const float* er2_w1   = (const float*)d_in[8];
    const float* codebook = (const float*)d_in[9];
    const float* dr1_w3   = (const float*)d_in[10];
    const float* dr1_w1   = (const float*)d_in[11];
    const float* dr2_w3   = (const float*)d_in[12];
    const float* dr2_w1   = (const float*)d_in[13];
    const float* dt1_w    = (const float*)d_in[14];
    const float* dt1_b    = (const float*)d_in[15];
    const float* dt2_w    = (const float*)d_in[16];
    const float* dt2_b    = (const float*)d_in[17];

    float* recon = (float*)d_out;
    float* loss  = recon + 1572864;

    char* ws = (char*)d_ws;
    size_t off = 0;
    auto alloc = [&](size_t bytes) { char* p = ws + off; off += (bytes + 255) & ~(size_t)255; return p; };
    ushort* X0   = (ushort*)alloc(16777216);   // bf16 NHWC 32x32 tensors
    ushort* X2   = (ushort*)alloc(16777216);
    ushort* X3   = (ushort*)alloc(16777216);
    ushort* X4   = (ushort*)alloc(16777216);
    ushort* xpk  = (ushort*)alloc(8388608);    // [32][128][4][32][8] bf16
    ushort* wpk_er13 = (ushort*)alloc(1179648);
    ushort* wpk_er23 = (ushort*)alloc(1179648);
    ushort* wpk_dr13 = (ushort*)alloc(1179648);
    ushort* wpk_dr23 = (ushort*)alloc(1179648);
    ushort* wpk_er11 = (ushort*)alloc(131072);
    ushort* wpk_er21 = (ushort*)alloc(131072);
    ushort* wpk_dr11 = (ushort*)alloc(131072);
    ushort* wpk_dr21 = (ushort*)alloc(131072);
    ushort* wenc     = (ushort*)alloc(163840); // [10][256][32] bf16
    ushort* wdec     = (ushort*)alloc(221184); // [9][3][8][16][32] bf16
    ushort* apk      = (ushort*)alloc(32768);
    float*  benc     = (float*)alloc(1024);
    float*  bdec     = (float*)alloc(192);
    float*  en       = (float*)alloc(1024);
    float*  wct      = (float*)alloc(32768);   // [30][256] f32 (transposed)
    float*  wcb      = (float*)alloc(32768);
    float*  wcl      = (float*)alloc(32768);
    float*  wcr      = (float*)alloc(32768);
    float*  wcc      = (float*)alloc(12288);   // [12][256] f32

    // merged prep: packs + xpack + wdec/loss zeroing
    k_prep<<<26744, 256, 0, stream>>>(er1_w3, er2_w3, dr1_w3, dr2_w3,
                                      wpk_er13, wpk_er23, wpk_dr13, wpk_dr23,
                                      er1_w1, er2_w1, dr1_w1, dr2_w1,
                                      wpk_er11, wpk_er21, wpk_dr11, wpk_dr21,
                                      codebook, apk, en, x, xpk, wdec, loss);
    // merged weight composition (enc | dec)
    k_wcomp<<<512, 256, 0, stream>>>(enc_w1, enc_b1, enc_w2, enc_b2, wenc, benc,
                                     wct, wcb, wcl, wcr, wcc,
                                     dt1_w, dt1_b, dt2_w, dt2_b, wdec, bdec);

    // encoder (composed conv1∘conv2) + exact border fix: x -> X0
    k_enc_comp<<<1024, 128, 0, stream>>>(xpk, wenc, benc, X0);
    k_fix_border<<<4096, 256, 0, stream>>>(x, xpk, wct, wcb, wcl, wcr, wcc, X0);
    // fused res blocks (encoder)
    k_resblock<<<512, 256, 0, stream>>>(X0, wpk_er13, wpk_er11, X2);
    k_resblock<<<512, 256, 0, stream>>>(X2, wpk_er23, wpk_er21, X3);
    // VQ: X3 -> X4 (vq, no relu) + loss
    k_vq2<<<2048, 256, 0, stream>>>(X3, apk, en, codebook, X4, loss);
    // fused res blocks (decoder)
    k_resblock<<<512, 256, 0, stream>>>(X4, wpk_dr13, wpk_dr11, X0);
    k_resblock<<<512, 256, 0, stream>>>(X0, wpk_dr23, wpk_dr21, X2);
    // decoder (composed deconv1∘deconv2 + tanh): X2 -> recon
    k_dec_comp<<<512, 128, 0, stream>>>(X2, wdec, bdec, recon);
}

// Round 15
// 487.294 us; speedup vs baseline: 1.2217x; 1.0150x over previous
//
#include <hip/hip_runtime.h>
#include <math.h>

// VQ-VAE forward. R27: resblock LDS bank-conflict fix. The staging writes had
// octet stride 34*16=544B ≡ 8 banks -> 16 accesses/bank (2x the inherent 8),
// exactly matching SQ_LDS_BANK_CONFLICT=2.23M/dispatch. Fix: col stride 34->33
// with the two zero-pad logical cols (-1 and 32) SHARING one physical slot
// (32); read addr uses phys=min((unsigned)(col+dx),32u). Write stride becomes
// 528B ≡ 4 banks -> conflict-free. Same zeros, same accumulation order ->
// bit-identical. Everything else byte-identical to R26 (494.6 µs).

typedef unsigned short ushort;
typedef short bf16x8 __attribute__((ext_vector_type(8)));
typedef float f32x4 __attribute__((ext_vector_type(4)));

__device__ __forceinline__ ushort f2bf(float f) {
    unsigned u = __builtin_bit_cast(unsigned, f);
    unsigned r = (u + 0x7fffu + ((u >> 16) & 1u)) >> 16;
    return (ushort)r;
}
__device__ __forceinline__ float bfl(unsigned u) { return __builtin_bit_cast(float, u << 16); }
__device__ __forceinline__ float bfh(unsigned u) { return __builtin_bit_cast(float, u & 0xffff0000u); }

__device__ __forceinline__ unsigned relu_u(unsigned u) {
    unsigned m = (u >> 15) & 0x00010001u;
    return u & ~((m << 16) - m);
}
__device__ __forceinline__ uint4 relu4(uint4 v) {
    v.x = relu_u(v.x); v.y = relu_u(v.y); v.z = relu_u(v.z); v.w = relu_u(v.w);
    return v;
}

// ======================= merged prep: packs + xpack + zeroing =======================
// blockIdx ranges: [0,9216) c3x4 | [9216,10240) c1x1x4 | [10240,10305) vq pack
// | [10305,26689) xpack | [26689,26743) zero wdec | 26743 zero loss.
__global__ void k_prep(const float* __restrict__ w30, const float* __restrict__ w31,
                       const float* __restrict__ w32, const float* __restrict__ w33,
                       ushort* __restrict__ o30, ushort* __restrict__ o31,
                       ushort* __restrict__ o32, ushort* __restrict__ o33,
                       const float* __restrict__ w10, const float* __restrict__ w11,
                       const float* __restrict__ w12, const float* __restrict__ w13,
                       ushort* __restrict__ o10, ushort* __restrict__ o11,
                       ushort* __restrict__ o12, ushort* __restrict__ o13,
                       const float* __restrict__ cbk, ushort* __restrict__ apk,
                       float* __restrict__ en,
                       const float* __restrict__ x, ushort* __restrict__ xpk,
                       ushort* __restrict__ wdec, float* __restrict__ loss) {
    int b = blockIdx.x, tid = threadIdx.x;
    if (b < 9216) {                                   // ---- pack c3x4 ----
        int layer = b / 2304;
        int i = (b - layer * 2304) * 256 + tid;       // 589824
        const float* w = layer == 0 ? w30 : layer == 1 ? w31 : layer == 2 ? w32 : w33;
        ushort* o = layer == 0 ? o30 : layer == 1 ? o31 : layer == 2 ? o32 : o33;
        int kk = i & 31, co = (i >> 5) & 255, cb = (i >> 13) & 7, t = i >> 16;
        int ci = cb * 32 + kk, kh = t / 3, kw = t % 3;
        o[i] = f2bf(w[((co * 256 + ci) * 3 + kh) * 3 + kw]);
    } else if (b < 10240) {                           // ---- pack c1x1x4 ----
        int lb = b - 9216;
        int layer = lb >> 8;
        int i = (lb & 255) * 256 + tid;               // 65536
        const float* w = layer == 0 ? w10 : layer == 1 ? w11 : layer == 2 ? w12 : w13;
        ushort* o = layer == 0 ? o10 : layer == 1 ? o11 : layer == 2 ? o12 : o13;
        int kk = i & 31, co = (i >> 5) & 255, cb = (i >> 13) & 7;
        o[i] = f2bf(w[co * 256 + cb * 32 + kk]);
    } else if (b < 10305) {                           // ---- pack vq ----
        int lb = b - 10240;
        if (lb < 64) {
            int i = lb * 256 + tid;
            int j = i & 7, lane = (i >> 3) & 63, s = (i >> 9) & 1, t = i >> 10;
            int code = t * 16 + (lane & 15);
            int dim = s * 32 + (lane >> 4) * 8 + j;
            apk[i] = f2bf(cbk[code * 64 + dim]);
        } else {
            int code = tid;
            float s = 0.f;
            for (int d = 0; d < 64; ++d) { float v = cbk[code * 64 + d]; s += v * v; }
            en[code] = s;
        }
    } else if (b < 26689) {                           // ---- xpack ----
        int i = (b - 10305) * 256 + tid;              // 4,194,304
        int j = i & 7, ow = (i >> 3) & 31, q = (i >> 8) & 3, r = (i >> 10) & 127, n = i >> 17;
        int k = q * 8 + j;
        float v = 0.f;
        if (k < 30) {
            int ci = k % 3, kw = k / 3;
            int col = 4 * ow - 3 + kw;
            if ((unsigned)col < 128u) v = x[((n * 3 + ci) * 128 + r) * 128 + col];
        }
        xpk[i] = f2bf(v);
    } else if (b < 26743) {                           // ---- zero wdec ----
        int idx = (b - 26689) * 256 + tid;            // 13824 x 16B = 221184 B
        uint4 z; z.x = 0; z.y = 0; z.z = 0; z.w = 0;
        *(uint4*)(wdec + idx * 8) = z;
    } else {                                          // ---- zero loss ----
        if (tid == 0) loss[0] = 0.f;
    }
}

// ======================= merged weight composition (enc | dec) ==================
__global__ __launch_bounds__(256) void k_wcomp(const float* __restrict__ w1,
                                               const float* __restrict__ b1f,
                                               const float* __restrict__ w2,
                                               const float* __restrict__ b2f,
                                               ushort* __restrict__ wenc,
                                               float* __restrict__ benc,
                                               float* __restrict__ wct,
                                               float* __restrict__ wcb,
                                               float* __restrict__ wcl,
                                               float* __restrict__ wcr,
                                               float* __restrict__ wcc,
                                               const float* __restrict__ dt1,
                                               const float* __restrict__ dt1b,
                                               const float* __restrict__ dt2,
                                               const float* __restrict__ dt2b,
                                               ushort* __restrict__ wdec,
                                               float* __restrict__ bdec) {
    __shared__ float sA[12288];
    __shared__ float sB[4096];
    __shared__ float part[2400];
    int tid = threadIdx.x;

    if (blockIdx.x < 256) {
        // ================= encoder branch (sw1 = sA, sw2 = sB) =================
        int co = blockIdx.x;
        for (int i = tid; i < 12288; i += 256) sA[i] = w1[i];
        for (int i = tid; i < 4096; i += 256) sB[i] = w2[co * 4096 + i];
        __syncthreads();

        {   // bias
            float s = 0.f;
#pragma unroll
            for (int t = 0; t < 16; ++t) s += sB[tid * 16 + t];
            float pb = b1f[tid] * s;
#pragma unroll
            for (int m = 1; m < 64; m <<= 1) pb += __shfl_xor(pb, m);
            if ((tid & 63) == 0) part[tid >> 6] = pb;
        }
        __syncthreads();
        if (tid == 0) benc[co] = b2f[co] + part[0] + part[1] + part[2] + part[3];

        if (tid < 240) {               // t = y*24 + ci*8 + ms
            int y = tid / 24, rem = tid % 24, ci = rem / 8, ms = rem % 8;
            int na = 0, aa[2], h1[2];
#pragma unroll
            for (int a = 0; a < 4; ++a) {
                int k1 = y - 2 * a;
                if ((unsigned)k1 < 4u) { aa[na] = a; h1[na] = k1; ++na; }
            }
            float acc10[10];
#pragma unroll
            for (int xx = 0; xx < 10; ++xx) acc10[xx] = 0.f;
            for (int m = ms * 32; m < ms * 32 + 32; ++m) {
                for (int pa = 0; pa < na; ++pa) {
                    float4 a2 = *(const float4*)&sB[m * 16 + aa[pa] * 4];
                    float4 a1 = *(const float4*)&sA[m * 48 + ci * 16 + h1[pa] * 4];
                    acc10[0] += a2.x * a1.x; acc10[1] += a2.x * a1.y; acc10[2] += a2.x * a1.z; acc10[3] += a2.x * a1.w;
                    acc10[2] += a2.y * a1.x; acc10[3] += a2.y * a1.y; acc10[4] += a2.y * a1.z; acc10[5] += a2.y * a1.w;
                    acc10[4] += a2.z * a1.x; acc10[5] += a2.z * a1.y; acc10[6] += a2.z * a1.z; acc10[7] += a2.z * a1.w;
                    acc10[6] += a2.w * a1.x; acc10[7] += a2.w * a1.y; acc10[8] += a2.w * a1.z; acc10[9] += a2.w * a1.w;
                }
            }
#pragma unroll
            for (int xx = 0; xx < 10; ++xx) part[tid * 10 + xx] = acc10[xx];
        }
        __syncthreads();
        for (int w = tid; w < 320; w += 256) {
            if (w < 300) {
                int y = w / 30, r = w % 30, ci = r / 10, xx = r % 10;
                float s = 0.f;
#pragma unroll
                for (int ms = 0; ms < 8; ++ms) s += part[((y * 24 + ci * 8) + ms) * 10 + xx];
                wenc[(y * 256 + co) * 32 + xx * 3 + ci] = f2bf(s);
            } else {
                int j = w - 300;
                int y = j >> 1;
                wenc[(y * 256 + co) * 32 + 30 + (j & 1)] = 0;
            }
        }

        // ---- border-correction weights from LDS ----
        if (tid < 30 || (tid >= 32 && tid < 62)) {
            bool top = tid < 30;
            int t = top ? tid : tid - 32;
            int xx = t / 3, ci = t % 3;
            int k2hf = top ? 0 : 3, k1hf = top ? 3 : 0;
            float s = 0.f;
            for (int m = 0; m < 256; ++m)
                for (int k2w = 0; k2w < 4; ++k2w) {
                    int k1w = xx - 2 * k2w;
                    if ((unsigned)k1w < 4u)
                        s += sB[m * 16 + k2hf * 4 + k2w] * sA[m * 48 + ci * 16 + k1hf * 4 + k1w];
                }
            (top ? wct : wcb)[t * 256 + co] = s;
        } else if ((tid >= 64 && tid < 94) || (tid >= 96 && tid < 126)) {
            bool left = tid < 94;
            int t = left ? tid - 64 : tid - 96;
            int y = t / 3, ci = t % 3;
            int k2wf = left ? 0 : 3, k1wf = left ? 3 : 0;
            float s = 0.f;
            for (int m = 0; m < 256; ++m)
                for (int k2h = 0; k2h < 4; ++k2h) {
                    int k1h = y - 2 * k2h;
                    if ((unsigned)k1h < 4u)
                        s += sB[m * 16 + k2h * 4 + k2wf] * sA[m * 48 + ci * 16 + k1h * 4 + k1wf];
                }
            (left ? wcl : wcr)[t * 256 + co] = s;
        } else if (tid >= 128 && tid < 140) {
            int c = (tid - 128) / 3, ci = (tid - 128) % 3;
            int k2h = (c >> 1) ? 3 : 0, k2w = (c & 1) ? 3 : 0;
            int k1h = 3 - k2h, k1w = 3 - k2w;
            float s = 0.f;
            for (int m = 0; m < 256; ++m)
                s += sB[m * 16 + k2h * 4 + k2w] * sA[m * 48 + ci * 16 + k1h * 4 + k1w];
            wcc[(c * 3 + ci) * 256 + co] = s;
        }
    } else {
        // ================= decoder branch (s2 = sA, s1 = sB) =================
        int ci = blockIdx.x - 256;
        for (int i = tid; i < 4096; i += 256) sB[i] = dt1[ci * 4096 + i];
        for (int i = tid; i < 12288; i += 256) sA[i] = dt2[i];
        __syncthreads();

        if (ci == 0 && tid < 48) {
            int o = tid >> 4, p = tid & 15, py = p >> 2, px = p & 3;
            int c0 = (py + 1) & 1, d0 = (px + 1) & 1;
            float s = dt2b[o];
            for (int m = 0; m < 256; ++m) {
                float t2 = sA[m * 48 + o * 16 + c0 * 4 + d0] + sA[m * 48 + o * 16 + c0 * 4 + d0 + 2]
                         + sA[m * 48 + o * 16 + (c0 + 2) * 4 + d0] + sA[m * 48 + o * 16 + (c0 + 2) * 4 + d0 + 2];
                s += dt1b[m] * t2;
            }
            bdec[tid] = s;
        }

        if (tid < 240) {
            int y = tid / 24, rem = tid % 24, o = rem / 8, ms = rem % 8;
            int na = 0, aa[2], cc[2];
#pragma unroll
            for (int a = 0; a < 4; ++a) {
                int c = y - 2 * a;
                if ((unsigned)c < 4u) { aa[na] = a; cc[na] = c; ++na; }
            }
            float acc10[10];
#pragma unroll
            for (int xx = 0; xx < 10; ++xx) acc10[xx] = 0.f;
            for (int m = ms * 32; m < ms * 32 + 32; ++m) {
                for (int pa = 0; pa < na; ++pa) {
                    float4 d1 = *(const float4*)&sB[m * 16 + aa[pa] * 4];
                    float4 d2 = *(const float4*)&sA[m * 48 + o * 16 + cc[pa] * 4];
                    acc10[0] += d1.x * d2.x; acc10[1] += d1.x * d2.y; acc10[2] += d1.x * d2.z; acc10[3] += d1.x * d2.w;
                    acc10[2] += d1.y * d2.x; acc10[3] += d1.y * d2.y; acc10[4] += d1.y * d2.z; acc10[5] += d1.y * d2.w;
                    acc10[4] += d1.z * d2.x; acc10[5] += d1.z * d2.y; acc10[6] += d1.z * d2.z; acc10[7] += d1.z * d2.w;
                    acc10[6] += d1.w * d2.x; acc10[7] += d1.w * d2.y; acc10[8] += d1.w * d2.z; acc10[9] += d1.w * d2.w;
                }
            }
#pragma unroll
            for (int xx = 0; xx < 10; ++xx) part[tid * 10 + xx] = acc10[xx];
        }
        __syncthreads();
        for (int w = tid; w < 300; w += 256) {
            int y = w / 30, r = w % 30, o = r / 10, xx = r % 10;
            float s = 0.f;
#pragma unroll
            for (int ms = 0; ms < 8; ++ms) s += part[((y * 24 + o * 8) + ms) * 10 + xx];
            int du = (y < 3) ? 1 : (y < 7) ? 0 : -1;
            int py = y - 3 + 4 * du;
            int dv = (xx < 3) ? 1 : (xx < 7) ? 0 : -1;
            int px = xx - 3 + 4 * dv;
            int t = (du + 1) * 3 + (dv + 1);
            int cb2 = ci >> 5, kk = ci & 31;
            wdec[((((t * 3 + o) * 8 + cb2) * 16 + py * 4 + px) * 32) + kk] = f2bf(s);
        }
    }
}

// ======================= composed encoder conv: 3->256 k10 s4, 128->32 =========
__global__ __launch_bounds__(128) void k_enc_comp(const ushort* __restrict__ xpk,
                                                  const ushort* __restrict__ wenc,
                                                  const float* __restrict__ benc,
                                                  ushort* __restrict__ obf) {
    int tid = threadIdx.x, lane = tid & 63, wv = tid >> 6;
    int q = lane >> 4, l15 = lane & 15;
    int b = blockIdx.x;
    int mblk = b & 7, coslab = (b >> 3) & 3, n = b >> 5;
    int R0 = mblk * 4 + wv * 2;
    int aoff = (coslab * 64 + l15) * 32 + q * 8;

    f32x4 acc[4][4];
#pragma unroll
    for (int at = 0; at < 4; ++at)
#pragma unroll
        for (int bt = 0; bt < 4; ++bt) acc[at][bt] = 0.f;

    for (int t = 0; t < 10; ++t) {
        bf16x8 af[4];
#pragma unroll
        for (int at = 0; at < 4; ++at)
            af[at] = *(const bf16x8*)(wenc + t * 8192 + aoff + at * 512);
#pragma unroll
        for (int bt2 = 0; bt2 < 2; ++bt2) {
            int irow = 4 * (R0 + bt2) + t - 3;
            if ((unsigned)irow >= 128u) continue;      // x zero padding -> skip
            bf16x8 bf[2];
#pragma unroll
            for (int hb = 0; hb < 2; ++hb) {
                int ow = hb * 16 + l15;
                bf[hb] = *(const bf16x8*)(xpk + ((((long)n * 128 + irow) * 4 + q) * 32 + ow) * 8);
            }
#pragma unroll
            for (int at = 0; at < 4; ++at)
#pragma unroll
                for (int hb = 0; hb < 2; ++hb)
                    acc[at][bt2 * 2 + hb] = __builtin_amdgcn_mfma_f32_16x16x32_bf16(
                        af[at], bf[hb], acc[at][bt2 * 2 + hb], 0, 0, 0);
        }
    }

    int co_base = coslab * 64;
#pragma unroll
    for (int at = 0; at < 4; ++at) {
        int co_t = co_base + at * 16 + q * 4;
        float4 b4 = *(const float4*)(benc + co_t);
        float bv[4] = {b4.x, b4.y, b4.z, b4.w};
#pragma unroll
        for (int bt = 0; bt < 4; ++bt) {
            int m = R0 * 32 + bt * 16 + l15;
            long oaddr = ((long)n * 1024 + m) * 256 + co_t;
            float v[4];
#pragma unroll
            for (int r = 0; r < 4; ++r) v[r] = acc[at][bt][r] + bv[r];
            uint2 pk;
            pk.x = (unsigned)f2bf(v[0]) | ((unsigned)f2bf(v[1]) << 16);
            pk.y = (unsigned)f2bf(v[2]) | ((unsigned)f2bf(v[3]) << 16);
            *(uint2*)(obf + oaddr) = pk;
        }
    }
}

// ======================= border fix (parallel, R19-verified; xpk addr R22) =====
__global__ __launch_bounds__(256) void k_fix_border(const float* __restrict__ x,
                                                    const ushort* __restrict__ xpk,
                                                    const float* __restrict__ wct,
                                                    const float* __restrict__ wcb,
                                                    const float* __restrict__ wcl,
                                                    const float* __restrict__ wcr,
                                                    const float* __restrict__ wcc,
                                                    ushort* __restrict__ X0) {
    int b = blockIdx.x;
    int n = b >> 7, job = b & 127;
    if (job >= 124) return;
    int co = threadIdx.x;

    auto dot_tb = [&](const float* __restrict__ w, int row, int qq) -> float {
        const ushort* xr = xpk + ((long)n * 128 + row) * 1024;   // [q(4)][ow(32)][8]
        float s = 0.f;
        for (int k = 0; k < 30; ++k)
            s += w[k * 256 + co] * bfl((unsigned)xr[(k >> 3) * 256 + qq * 8 + (k & 7)]);
        return s;
    };
    auto dot_lr = [&](const float* __restrict__ w, int p, int colofs) -> float {
        float s = 0.f;
        for (int y = 0; y < 10; ++y) {
            int row = 4 * p - 3 + y;
            if ((unsigned)row >= 128u) continue;
            for (int ci = 0; ci < 3; ++ci)
                s += w[(y * 3 + ci) * 256 + co] * x[((long)(n * 3 + ci) * 128 + row) * 128 + colofs];
        }
        return s;
    };
    auto corner = [&](int c, int row, int colofs) -> float {
        float s = 0.f;
        for (int ci = 0; ci < 3; ++ci)
            s += wcc[(c * 3 + ci) * 256 + co] * x[((long)(n * 3 + ci) * 128 + row) * 128 + colofs];
        return s;
    };

    int m;
    float corr;
    if (job < 32) {                       // top row p=0
        int qq = job;
        m = qq;
        corr = dot_tb(wct, 0, qq);
        if (qq == 0)  corr += dot_lr(wcl, 0, 0)   - corner(0, 0, 0);
        if (qq == 31) corr += dot_lr(wcr, 0, 127) - corner(1, 0, 127);
    } else if (job < 64) {                // bottom row p=31
        int qq = job - 32;
        m = 992 + qq;
        corr = dot_tb(wcb, 127, qq);
        if (qq == 0)  corr += dot_lr(wcl, 31, 0)   - corner(2, 127, 0);
        if (qq == 31) corr += dot_lr(wcr, 31, 127) - corner(3, 127, 127);
    } else if (job < 94) {                // left col q=0, p=1..30
        int p = job - 63;
        m = 32 * p;
        corr = dot_lr(wcl, p, 0);
    } else {                              // right col q=31, p=1..30
        int p = job - 93;
        m = 32 * p + 31;
        corr = dot_lr(wcr, p, 127);
    }

    ushort* ptr = X0 + ((long)n * 1024 + m) * 256 + co;
    float v = bfl((unsigned)(*ptr));
    *ptr = f2bf(v - corr);
}

// ======================= fused res block (R27: conflict-free staging layout) ===
// sS layout: [row(4)][oct(32)][col(33)][8] ushorts = 67584 B. Physical col 32
// is the SHARED zero-pad for logical cols -1 and 32; read addr uses
// min((unsigned)(col0+dx), 32). Octet stride 33*16=528B ≡ 4 banks -> staging
// writes conflict-free (were 16-access/bank at stride 34). Data/order
// identical to R26 -> bit-identical output.
__global__ __launch_bounds__(256, 2) void k_resblock(const ushort* __restrict__ xin,
                                                     const ushort* __restrict__ w3pk,
                                                     const ushort* __restrict__ w1pk,
                                                     ushort* __restrict__ obf) {
    __shared__ __align__(16) ushort sS[4 * 32 * 33 * 8];   // 67584 B

    int tid = threadIdx.x, lane = tid & 63, wv = tid >> 6;
    int q = lane >> 4, l15 = lane & 15;
    int b = blockIdx.x;                              // 32n * 16 rowpairs
    int rp = b & 15, n = b >> 4;
    int R0 = rp * 2;

    int brr[4], bcol0[4];
#pragma unroll
    for (int bt = 0; bt < 4; ++bt) {
        int p = bt * 16 + l15;
        brr[bt] = p >> 5; bcol0[bt] = p & 31;        // logical col 0..31
    }
    int aoff = (wv * 64 + l15) * 32 + q * 8;

    // ---- stage the whole tile: contiguous global bursts, conflict-free writes ----
#pragma unroll
    for (int it = 0; it < 16; ++it) {
        int idx = it * 256 + tid;
        int j = idx & 31, c = (idx >> 5) & 31, r = idx >> 10;
        int hh2 = R0 - 1 + r;
        uint4 v;
        if ((unsigned)hh2 < 32u)
            v = relu4(*(const uint4*)(xin + (((long)n * 32 + hh2) * 32 + c) * 256 + j * 8));
        else { v.x = 0; v.y = 0; v.z = 0; v.w = 0; }
        *(uint4*)&sS[((r * 32 + j) * 33 + c) * 8] = v;
    }
    if (tid < 128) {   // zero the shared pad slot (phys col 32) for all (r, j)
        int r = tid >> 5, j = tid & 31;
        uint4 z; z.x = 0; z.y = 0; z.z = 0; z.w = 0;
        *(uint4*)&sS[((r * 32 + j) * 33 + 32) * 8] = z;
    }

    f32x4 acc[4][4];
#pragma unroll
    for (int at = 0; at < 4; ++at)
#pragma unroll
        for (int bt = 0; bt < 4; ++bt) acc[at][bt] = 0.f;

    // A pipeline: rolling 3-buffer, depth 2, cross-cb (R22-verified)
    bf16x8 afA[3][4];
    {
        const ushort* wb0 = w3pk + aoff;
#pragma unroll
        for (int at = 0; at < 4; ++at) afA[0][at] = *(const bf16x8*)(wb0 + at * 512);
#pragma unroll
        for (int at = 0; at < 4; ++at) afA[1][at] = *(const bf16x8*)(wb0 + 65536 + at * 512);
    }
    __syncthreads();                                 // tile + pad visible

    // ---- 3x3: 8 cb x 9 taps, NO barriers ----
    for (int cb = 0; cb < 8; ++cb) {
        const ushort* wb = w3pk + (long)cb * 8192 + aoff;
        const ushort* wbn = w3pk + (long)(cb + 1) * 8192 + aoff;   // used if cb<7
        int qo = cb * 4 + q;                         // global ci-octet for this wave

#pragma unroll
        for (int t = 0; t < 9; ++t) {
            if (t < 7) {
#pragma unroll
                for (int at = 0; at < 4; ++at)
                    afA[(t + 2) % 3][at] = *(const bf16x8*)(wb + (long)(t + 2) * 65536 + at * 512);
            } else if (cb < 7) {
#pragma unroll
                for (int at = 0; at < 4; ++at)
                    afA[(t + 2) % 3][at] = *(const bf16x8*)(wbn + (long)(t - 7) * 65536 + at * 512);
            }
            int taprow = t / 3, dx = t % 3 - 1;
            bf16x8 bfr[4];
#pragma unroll
            for (int bt = 0; bt < 4; ++bt) {
                unsigned uc = (unsigned)(bcol0[bt] + dx);
                int phys = uc > 32u ? 32 : (int)uc;  // pad slot for logical -1/32
                bfr[bt] = *(const bf16x8*)&sS[(((brr[bt] + taprow) * 32 + qo) * 33 + phys) * 8];
            }
#pragma unroll
            for (int at = 0; at < 4; ++at)
#pragma unroll
                for (int bt = 0; bt < 4; ++bt)
                    acc[at][bt] = __builtin_amdgcn_mfma_f32_16x16x32_bf16(afA[t % 3][at], bfr[bt],
                                                                          acc[at][bt], 0, 0, 0);
        }
    }
    __syncthreads();                                 // all sS reads done -> reuse

    // ---- 3x3 epilogue: relu -> bf16 -> exchange (aliased into sS) ----
#pragma unroll
    for (int at = 0; at < 4; ++at) {
        int co_t = wv * 64 + at * 16 + q * 4;
#pragma unroll
        for (int bt = 0; bt < 4; ++bt) {
            int px = bt * 16 + l15;
            uint2 pk;
            pk.x = (unsigned)f2bf(fmaxf(acc[at][bt][0], 0.f))
                 | ((unsigned)f2bf(fmaxf(acc[at][bt][1], 0.f)) << 16);
            pk.y = (unsigned)f2bf(fmaxf(acc[at][bt][2], 0.f))
                 | ((unsigned)f2bf(fmaxf(acc[at][bt][3], 0.f)) << 16);
            *(uint2*)&sS[px * 256 + (co_t ^ ((px & 7) << 3))] = pk;
        }
    }
    __syncthreads();

    // ---- 1x1 over 8 ci-slabs from exchange; distance-1 A-prefetch ----
    f32x4 acc2[4][4];
#pragma unroll
    for (int at = 0; at < 4; ++at)
#pragma unroll
        for (int bt = 0; bt < 4; ++bt) acc2[at][bt] = 0.f;

    bf16x8 af1c[4], af1n[4];
#pragma unroll
    for (int at = 0; at < 4; ++at) af1c[at] = *(const bf16x8*)(w1pk + aoff + at * 512);

    for (int cb = 0; cb < 8; ++cb) {
        if (cb + 1 < 8) {
            const ushort* wb1n = w1pk + (long)(cb + 1) * 8192 + aoff;
#pragma unroll
            for (int at = 0; at < 4; ++at) af1n[at] = *(const bf16x8*)(wb1n + at * 512);
        }
        bf16x8 bf1[4];
#pragma unroll
        for (int bt = 0; bt < 4; ++bt) {
            int px = bt * 16 + l15;
            bf1[bt] = *(const bf16x8*)&sS[px * 256 + ((cb * 32 + q * 8) ^ ((px & 7) << 3))];
        }
#pragma unroll
        for (int at = 0; at < 4; ++at)
#pragma unroll
            for (int bt = 0; bt < 4; ++bt)
                acc2[at][bt] = __builtin_amdgcn_mfma_f32_16x16x32_bf16(af1c[at], bf1[bt],
                                                                      acc2[at][bt], 0, 0, 0);
        if (cb + 1 < 8) {
#pragma unroll
            for (int at = 0; at < 4; ++at) af1c[at] = af1n[at];
        }
    }

#pragma unroll
    for (int at = 0; at < 4; ++at) {
        int co_t = wv * 64 + at * 16 + q * 4;
#pragma unroll
        for (int bt = 0; bt < 4; ++bt) {
            int m = R0 * 32 + bt * 16 + l15;
            long oaddr = ((long)n * 1024 + m) * 256 + co_t;
            uint2 rr = *(const uint2*)(xin + oaddr);
            float v[4];
            v[0] = acc2[at][bt][0] + bfl(rr.x);
            v[1] = acc2[at][bt][1] + bfh(rr.x);
            v[2] = acc2[at][bt][2] + bfl(rr.y);
            v[3] = acc2[at][bt][3] + bfh(rr.y);
            uint2 pk;
            pk.x = (unsigned)f2bf(v[0]) | ((unsigned)f2bf(v[1]) << 16);
            pk.y = (unsigned)f2bf(v[2]) | ((unsigned)f2bf(v[3]) << 16);
            *(uint2*)(obf + oaddr) = pk;
        }
    }
}

// ======================= VQ via MFMA (bf16 out) =======================
__global__ __launch_bounds__(256) void k_vq2(const ushort* __restrict__ zb,
                                             const ushort* __restrict__ apk,
                                             const float* __restrict__ en,
                                             const float* __restrict__ cbf,
                                             ushort* __restrict__ vqb,
                                             float* __restrict__ loss) {
    __shared__ int sIdx[64];
    __shared__ float sLoss[64];
    int tid = threadIdx.x, lane = tid & 63, wv = tid >> 6;
    int q = lane >> 4, l15 = lane & 15;
    int r0 = blockIdx.x * 64;
    int R = r0 + wv * 16;

    const ushort* zp = zb + ((long)(R + l15)) * 64 + q * 8;
    bf16x8 b0 = *(const bf16x8*)zp;
    bf16x8 b1 = *(const bf16x8*)(zp + 32);

    float z2 = 0.f;
    {
        const unsigned* u0 = (const unsigned*)&b0;
        const unsigned* u1 = (const unsigned*)&b1;
#pragma unroll
        for (int i = 0; i < 4; ++i) {
            float a = bfl(u0[i]), bb = bfh(u0[i]);
            float c = bfl(u1[i]), d = bfh(u1[i]);
            z2 += a * a + bb * bb + c * c + d * d;
        }
    }

    float best = 3.4e38f;
    int bidx = 0;
#pragma unroll
    for (int t = 0; t < 16; ++t) {
        bf16x8 a0 = *(const bf16x8*)(apk + ((t * 2 + 0) * 64 + lane) * 8);
        bf16x8 a1 = *(const bf16x8*)(apk + ((t * 2 + 1) * 64 + lane) * 8);
        f32x4 acc = {0.f, 0.f, 0.f, 0.f};
        acc = __builtin_amdgcn_mfma_f32_16x16x32_bf16(a0, b0, acc, 0, 0, 0);
        acc = __builtin_amdgcn_mfma_f32_16x16x32_bf16(a1, b1, acc, 0, 0, 0);
        float4 e4 = *(const float4*)(en + t * 16 + q * 4);
        float sc[4] = {e4.x - 2.f * acc[0], e4.y - 2.f * acc[1],
                       e4.z - 2.f * acc[2], e4.w - 2.f * acc[3]};
#pragma unroll
        for (int r = 0; r < 4; ++r) {
            int code = t * 16 + q * 4 + r;
            if (sc[r] < best) { best = sc[r]; bidx = code; }
        }
    }
#pragma unroll
    for (int m = 16; m <= 32; m <<= 1) {
        float ob = __shfl_xor(best, m);
        int oi = __shfl_xor(bidx, m);
        if (ob < best || (ob == best && oi < bidx)) { best = ob; bidx = oi; }
        z2 += __shfl_xor(z2, m);
    }
    if (q == 0) {
        sIdx[wv * 16 + l15] = bidx;
        sLoss[wv * 16 + l15] = best + z2;
    }
    __syncthreads();

    if (wv == 0) {
        float l = sLoss[lane];
#pragma unroll
        for (int m = 1; m < 64; m <<= 1) l += __shfl_xor(l, m);
        if (lane == 0) atomicAdd(loss, l * (1.25f / 8388608.f));
    }

    unsigned* vb = (unsigned*)(vqb + (long)r0 * 64);
#pragma unroll
    for (int k = 0; k < 8; ++k) {
        int i = k * 256 + tid;
        int rl = i >> 5, jp = i & 31;
        int idx = sIdx[rl];
        float v0 = cbf[idx * 64 + 2 * jp];
        float v1 = cbf[idx * 64 + 2 * jp + 1];
        vb[i] = (unsigned)f2bf(v0) | ((unsigned)f2bf(v1) << 16);
    }
}

// ======================= composed decoder deconv: 256->3 k10 s4, 32->128 ========
// Coalesced epilogue (verified bit-identical in R20).
__global__ __launch_bounds__(128, 2) void k_dec_comp(const ushort* __restrict__ xin,
                                                     const ushort* __restrict__ wdec,
                                                     const float* __restrict__ bdec,
                                                     float* __restrict__ out) {
    constexpr int BUFU = 3 * 4 * 34 * 8;             // 3264 ushorts
    constexpr int WLDS = 2 * BUFU;
    __shared__ __align__(16) ushort sX[2 * WLDS];    // 26112 B
    __shared__ __align__(16) float sOut[3072];       // 12288 B

    int tid = threadIdx.x, lane = tid & 63, wv = tid >> 6;
    int q = lane >> 4, l15 = lane & 15;
    int b = blockIdx.x;                              // 32n * 16rp
    int rp = b & 15, n = b >> 4;
    int U = rp * 2 + wv;
    ushort* sW = sX + wv * WLDS;

    if (lane < 48) {
        int cc = (lane & 1) ? 33 : 0;
        int sq = lane >> 1;
        uint4 z; z.x = z.y = z.z = z.w = 0;
        *(uint4*)&sW[(sq * 34 + cc) * 8] = z;
    }
    int scol = lane >> 1, j0 = (lane & 1) * 2;

    f32x4 acc[3][2];
#pragma unroll
    for (int o = 0; o < 3; ++o)
#pragma unroll
        for (int bt = 0; bt < 2; ++bt) acc[o][bt] = 0.f;

    uint4 sreg[3][2];
    auto stage_load = [&](int cb2) {
#pragma unroll
        for (int r = 0; r < 3; ++r) {
            int hh = U - 1 + r;
            bool valid = (unsigned)hh < 32u;
            long off = (((long)n * 32 + hh) * 32 + scol) * 256 + cb2 * 32 + j0 * 8;
#pragma unroll
            for (int k = 0; k < 2; ++k) {
                uint4 v;
                if (valid) v = *(const uint4*)(xin + off + k * 8);
                else { v.x = 0; v.y = 0; v.z = 0; v.w = 0; }
                sreg[r][k] = v;
            }
        }
    };
    auto write_stage = [&](int pbuf) {
        ushort* bufp = sW + pbuf * BUFU;
#pragma unroll
        for (int r = 0; r < 3; ++r)
#pragma unroll
            for (int k = 0; k < 2; ++k)
                *(uint4*)&bufp[((r * 4 + j0 + k) * 34 + scol + 1) * 8] = sreg[r][k];
    };

    stage_load(0);
    write_stage(0);

    for (int cb = 0; cb < 8; ++cb) {
        ushort* bufp = sW + (cb & 1) * BUFU;
        if (cb + 1 < 8) stage_load(cb + 1);
        const ushort* wb = wdec + (long)cb * 512 + l15 * 32 + q * 8;
#pragma unroll
        for (int t = 0; t < 9; ++t) {
            int du = t / 3 - 1, dv = t % 3 - 1;
            bf16x8 bfr[2];
#pragma unroll
            for (int bt = 0; bt < 2; ++bt)
                bfr[bt] = *(const bf16x8*)&bufp[(((du + 1) * 4 + q) * 34 + bt * 16 + l15 + 1 + dv) * 8];
#pragma unroll
            for (int o = 0; o < 3; ++o) {
                bf16x8 af = *(const bf16x8*)(wb + (long)(t * 3 + o) * 4096);
#pragma unroll
                for (int bt = 0; bt < 2; ++bt)
                    acc[o][bt] = __builtin_amdgcn_mfma_f32_16x16x32_bf16(af, bfr[bt], acc[o][bt], 0, 0, 0);
            }
        }
        if (cb + 1 < 8) write_stage((cb + 1) & 1);
    }

    // stage tanh'd output in LDS: sOut[((o*2+wv)*4+py)*128 + col]
#pragma unroll
    for (int o = 0; o < 3; ++o) {
#pragma unroll
        for (int bt = 0; bt < 2; ++bt) {
            int V = bt * 16 + l15;
#pragma unroll
            for (int r = 0; r < 4; ++r) {
                int p = q * 4 + r, py = p >> 2, px = p & 3;
                sOut[((o * 2 + wv) * 4 + py) * 128 + 4 * V + px] =
                    tanhf(acc[o][bt][r] + bdec[o * 16 + p]);
            }
        }
    }
    __syncthreads();

    // drain: 24 rows x 128 f32, 512B-contiguous bursts
#pragma unroll
    for (int i = 0; i < 6; ++i) {
        int idx = i * 128 + tid;                     // float4 index, 768 total
        int row = idx >> 5, colq = idx & 31;
        int o = row >> 3, rem = row & 7, wv2 = rem >> 2, py = rem & 3;
        long g = ((((long)n * 3 + o) * 128) + 4 * (rp * 2 + wv2) + py) * 128 + colq * 4;
        *(float4*)(out + g) = *(float4*)&sOut[row * 128 + colq * 4];
    }
}

// ======================= launcher =======================
extern "C" void kernel_launch(void* const* d_in, const int* in_sizes, int n_in,
                              void* d_out, int out_size, void* d_ws, size_t ws_size,
                              hipStream_t stream) {
    (void)in_sizes; (void)n_in; (void)out_size; (void)ws_size;
    const float* x        = (const float*)d_in[0];
    const float* enc_w1   = (const float*)d_in[1];
    const float* enc_b1   = (const float*)d_in[2];
    const float* enc_w2   = (const float*)d_in[3];
    const float* enc_b2   = (const float*)d_in[4];
    const float* er1_w3   = (const float*)d_in[5];
    const float* er1_w1   = (const float*)d_in[6];
    const float* er2_w3   = (const float*)d_in[7];
    const float* er2_w1   = (const float*)d_in[8];
    const float* codebook = (const float*)d_in[9];
    const float* dr1_w3   = (const float*)d_in[10];
    const float* dr1_w1   = (const float*)d_in[11];
    const float* dr2_w3   = (const float*)d_in[12];
    const float* dr2_w1   = (const float*)d_in[13];
    const float* dt1_w    = (const float*)d_in[14];
    const float* dt1_b    = (const float*)d_in[15];
    const float* dt2_w    = (const float*)d_in[16];
    const float* dt2_b    = (const float*)d_in[17];

    float* recon = (float*)d_out;
    float* loss  = recon + 1572864;

    char* ws = (char*)d_ws;
    size_t off = 0;
    auto alloc = [&](size_t bytes) { char* p = ws + off; off += (bytes + 255) & ~(size_t)255; return p; };
    ushort* X0   = (ushort*)alloc(16777216);   // bf16 NHWC 32x32 tensors
    ushort* X2   = (ushort*)alloc(16777216);
    ushort* X3   = (ushort*)alloc(16777216);
    ushort* X4   = (ushort*)alloc(16777216);
    ushort* xpk  = (ushort*)alloc(8388608);    // [32][128][4][32][8] bf16
    ushort* wpk_er13 = (ushort*)alloc(1179648);
    ushort* wpk_er23 = (ushort*)alloc(1179648);
    ushort* wpk_dr13 = (ushort*)alloc(1179648);
    ushort* wpk_dr23 = (ushort*)alloc(1179648);
    ushort* wpk_er11 = (ushort*)alloc(131072);
    ushort* wpk_er21 = (ushort*)alloc(131072);
    ushort* wpk_dr11 = (ushort*)alloc(131072);
    ushort* wpk_dr21 = (ushort*)alloc(131072);
    ushort* wenc     = (ushort*)alloc(163840); // [10][256][32] bf16
    ushort* wdec     = (ushort*)alloc(221184); // [9][3][8][16][32] bf16
    ushort* apk      = (ushort*)alloc(32768);
    float*  benc     = (float*)alloc(1024);
    float*  bdec     = (float*)alloc(192);
    float*  en       = (float*)alloc(1024);
    float*  wct      = (float*)alloc(32768);   // [30][256] f32 (transposed)
    float*  wcb      = (float*)alloc(32768);
    float*  wcl      = (float*)alloc(32768);
    float*  wcr      = (float*)alloc(32768);
    float*  wcc      = (float*)alloc(12288);   // [12][256] f32

    // merged prep: packs + xpack + wdec/loss zeroing
    k_prep<<<26744, 256, 0, stream>>>(er1_w3, er2_w3, dr1_w3, dr2_w3,
                                      wpk_er13, wpk_er23, wpk_dr13, wpk_dr23,
                                      er1_w1, er2_w1, dr1_w1, dr2_w1,
                                      wpk_er11, wpk_er21, wpk_dr11, wpk_dr21,
                                      codebook, apk, en, x, xpk, wdec, loss);
    // merged weight composition (enc | dec)
    k_wcomp<<<512, 256, 0, stream>>>(enc_w1, enc_b1, enc_w2, enc_b2, wenc, benc,
                                     wct, wcb, wcl, wcr, wcc,
                                     dt1_w, dt1_b, dt2_w, dt2_b, wdec, bdec);

    // encoder (composed conv1∘conv2) + exact border fix: x -> X0
    k_enc_comp<<<1024, 128, 0, stream>>>(xpk, wenc, benc, X0);
    k_fix_border<<<4096, 256, 0, stream>>>(x, xpk, wct, wcb, wcl, wcr, wcc, X0);
    // fused res blocks (encoder)
    k_resblock<<<512, 256, 0, stream>>>(X0, wpk_er13, wpk_er11, X2);
    k_resblock<<<512, 256, 0, stream>>>(X2, wpk_er23, wpk_er21, X3);
    // VQ: X3 -> X4 (vq, no relu) + loss
    k_vq2<<<2048, 256, 0, stream>>>(X3, apk, en, codebook, X4, loss);
    // fused res blocks (decoder)
    k_resblock<<<512, 256, 0, stream>>>(X4, wpk_dr13, wpk_dr11, X0);
    k_resblock<<<512, 256, 0, stream>>>(X0, wpk_dr23, wpk_dr21, X2);
    // decoder (composed deconv1∘deconv2 + tanh): X2 -> recon
    k_dec_comp<<<512, 128, 0, stream>>>(X2, wdec, bdec, recon);
}